// Round 4
// baseline (1527.858 us; speedup 1.0000x reference)
//
#include <hip/hip_runtime.h>

typedef unsigned short u16;
typedef unsigned int u32;
typedef __attribute__((ext_vector_type(8))) __bf16 bf16x8;
typedef __attribute__((ext_vector_type(4))) float f32x4;
typedef __attribute__((ext_vector_type(4))) u16 u16x4;

#define VOL 262144  // 64^3

__device__ __forceinline__ u16 f2bf(float f) {
  u32 u = __builtin_bit_cast(u32, f);
  u32 r = u + 0x7FFFu + ((u >> 16) & 1u);
  return (u16)(r >> 16);
}
__device__ __forceinline__ float bf2f(u16 h) {
  return __builtin_bit_cast(float, ((u32)h) << 16);
}
__device__ __forceinline__ bf16x8 ldsfrag(const u16* p) { return *(const bf16x8*)p; }

// pitch-64 XOR swizzle for attn buffers.
__device__ __forceinline__ int swA(int row, int col) {
  return row * 64 + (col ^ (((row ^ (row >> 3)) & 7) << 3));
}

// ---------------- weight pre-swizzle: Wq/Wk/Wv -> per-lane B-fragment order ----------------
// K order (s in [0,54)): dh(3) / dw(3) / dd(3) / c32(2).  nf in [0,12): cout group of 16.
__global__ __launch_bounds__(256) void swz_qkv(const float* __restrict__ Wq,
    const float* __restrict__ Wk, const float* __restrict__ Wv, u16* __restrict__ out) {
  int idx = blockIdx.x * 256 + threadIdx.x;
  if (idx >= 54 * 12 * 64 * 8) return;
  int jj = idx & 7;
  int lane = (idx >> 3) & 63;
  int t = idx >> 9;
  int nf = t % 12, s = t / 12;
  int dh = s / 18, sub = s % 18;
  int dw = sub / 6, dd = (sub >> 1) % 3, c32 = sub & 1;
  int coutg = nf * 16 + (lane & 15);
  int cin = c32 * 32 + (lane >> 4) * 8 + jj;
  const float* W = (coutg < 64) ? Wq : ((coutg < 128) ? Wk : Wv);
  int c = coutg & 63;
  out[idx] = f2bf(W[(c * 64 + cin) * 27 + dh * 9 + dw * 3 + dd]);
}

// K order (s in [0,162)): dh(3) / t(3: AVa,AVb,AVc 64-ch block) / dw(3) / dd(3) / c32(2)
__global__ __launch_bounds__(256) void swz_c(const float* __restrict__ Wc, u16* __restrict__ out) {
  int idx = blockIdx.x * 256 + threadIdx.x;
  if (idx >= 162 * 4 * 64 * 8) return;
  int jj = idx & 7;
  int lane = (idx >> 3) & 63;
  int nf = (idx >> 9) & 3;
  int s = idx >> 11;
  int dh = s / 54, rem = s % 54;
  int t = rem / 18, sub = rem % 18;
  int dw = sub / 6, dd = (sub >> 1) % 3, c32 = sub & 1;
  int cout = nf * 16 + (lane & 15);
  int cin = t * 64 + c32 * 32 + (lane >> 4) * 8 + jj;
  out[idx] = f2bf(Wc[(cout * 192 + cin) * 27 + dh * 9 + dw * 3 + dd]);
}

// ---------------- fused q/k/v conv3d (implicit GEMM, BM=128 = 2w x 64d, N=192, 8 waves) ----------------
// (512,2): do NOT force a tighter reg cap — round 2's (512,4) caused 1GB of spill traffic.
__global__ __launch_bounds__(512, 2) void conv_qkv(const float* __restrict__ x,
    const u16* __restrict__ BQ, const float* __restrict__ bq, const float* __restrict__ bk,
    const float* __restrict__ bv, u16* __restrict__ qb, u16* __restrict__ kb,
    u16* __restrict__ vb) {
  __shared__ __align__(16) u16 xT[4 * 66 * 72];  // [wwi][dpos 0..65][cin swizzled], pitch 72
  int tid = threadIdx.x;
  int id = blockIdx.x;
  int lin = (id & 7) * 512 + (id >> 3);  // XCD-chunk swizzle (4096 = 8*512)
  int b = lin >> 11, h = (lin >> 5) & 63, w0 = (lin & 31) * 2;
  int wave = tid >> 6, lane = tid & 63, r = lane & 15, g = lane >> 4;
  int mhalf = wave >> 2, nq = wave & 3;
  int pairid = tid >> 3, seg = tid & 7;
  if (tid < 256) {  // zero d-pad rows (dpos 0 and 65); swizzle identity there
    int wwi = tid >> 6, ci = tid & 63;
    xT[(wwi * 66 + 0) * 72 + ci] = 0;
    xT[(wwi * 66 + 65) * 72 + ci] = 0;
  }
  f32x4 acc[4][3];
#pragma unroll
  for (int i = 0; i < 4; ++i)
#pragma unroll
    for (int j = 0; j < 3; ++j)
#pragma unroll
      for (int e = 0; e < 4; ++e) acc[i][j][e] = 0.0f;

  for (int dh = 0; dh < 3; ++dh) {
    int hh = h + dh - 1;
    if ((unsigned)hh >= 64u) continue;
    __syncthreads();
#pragma unroll
    for (int pi = 0; pi < 2; ++pi) {
      int pair = pairid + 64 * pi;  // [0,128): wwi(4) x cin-pair(32)
      int wwi = pair >> 5, cin0 = (pair & 31) * 2;
      int ww = w0 + wwi - 1;
      float4 a0{}, a1{}, b0{}, b1{};
      if ((unsigned)ww < 64u) {
        const float* p = x + (size_t)(b * 64 + cin0) * VOL + hh * 4096 + ww * 64 + seg * 8;
        a0 = *(const float4*)p;        a1 = *(const float4*)(p + 4);
        b0 = *(const float4*)(p + VOL); b1 = *(const float4*)(p + VOL + 4);
      }
      u16 ua[8], ub[8];
      ua[0]=f2bf(a0.x); ua[1]=f2bf(a0.y); ua[2]=f2bf(a0.z); ua[3]=f2bf(a0.w);
      ua[4]=f2bf(a1.x); ua[5]=f2bf(a1.y); ua[6]=f2bf(a1.z); ua[7]=f2bf(a1.w);
      ub[0]=f2bf(b0.x); ub[1]=f2bf(b0.y); ub[2]=f2bf(b0.z); ub[3]=f2bf(b0.w);
      ub[4]=f2bf(b1.x); ub[5]=f2bf(b1.y); ub[6]=f2bf(b1.z); ub[7]=f2bf(b1.w);
      int rowb = wwi * 66;
#pragma unroll
      for (int di = 0; di < 8; ++di) {
        int dpos = seg * 8 + di + 1;
        *(u32*)&xT[(rowb + dpos) * 72 + (cin0 ^ (((dpos >> 3) & 7) << 3))] =
            (u32)ua[di] | ((u32)ub[di] << 16);
      }
    }
    __syncthreads();
#pragma unroll
    for (int sub = 0; sub < 18; ++sub) {
      int dw = sub / 6, dd = (sub >> 1) % 3, c32 = sub & 1;  // constants after unroll
      int colb = c32 * 32 + g * 8;
      int wwi = mhalf + dw;
      bf16x8 A[4];
#pragma unroll
      for (int l = 0; l < 4; ++l) {
        int dpos = l * 16 + r + dd;
        A[l] = ldsfrag(&xT[(wwi * 66 + dpos) * 72 + (colb ^ (((dpos >> 3) & 7) << 3))]);
      }
      const u16* Bp = BQ + ((size_t)((dh * 18 + sub) * 12 + nq * 3) * 64 + lane) * 8;
#pragma unroll
      for (int nf = 0; nf < 3; ++nf) {
        bf16x8 Bf = *(const bf16x8*)(Bp + nf * 512);
#pragma unroll
        for (int l = 0; l < 4; ++l)
          acc[l][nf] = __builtin_amdgcn_mfma_f32_16x16x32_bf16(A[l], Bf, acc[l][nf], 0, 0, 0);
      }
    }
  }
#pragma unroll
  for (int nf = 0; nf < 3; ++nf) {
    int coutg = (nq * 3 + nf) * 16 + r;
    int ten = coutg >> 6, c = coutg & 63;
    u16* dst = (ten == 0) ? qb : ((ten == 1) ? kb : vb);
    const float* bias = (ten == 0) ? bq : ((ten == 1) ? bk : bv);
    float bsv = bias[c];
#pragma unroll
    for (int l = 0; l < 4; ++l) {
      int d0 = l * 16 + g * 4;
      int idx = (b * 64 + c) * VOL + h * 4096 + (w0 + mhalf) * 64 + d0;
      u16x4 o;
#pragma unroll
      for (int jj = 0; jj < 4; ++jj) o[jj] = f2bf(acc[l][nf][jj] + bsv);
      *(u16x4*)(dst + idx) = o;
    }
  }
}

// ---------------- tiled transpose within each (b,c) volume: src[P][Q] -> dst[Q][P] ----------------
__global__ __launch_bounds__(256, 6) void ktranspose(const u16* __restrict__ src,
    u16* __restrict__ dst, int P, int Q) {
  __shared__ __align__(16) u16 tile[64 * 72];
  int tid = threadIdx.x;
  int id = blockIdx.x;
  int bc = id >> 6, t = id & 63;
  int qt = Q >> 6;
  int p0 = (t / qt) * 64, q0 = (t % qt) * 64;
  const u16* s = src + (size_t)bc * VOL;
  u16* d = dst + (size_t)bc * VOL;
#pragma unroll
  for (int it = 0; it < 2; ++it) {
    int c = tid + 256 * it;
    int i2 = c >> 3, sg = c & 7;
    *(uint4*)&tile[i2 * 72 + ((sg * 8) ^ (((i2 >> 3) & 7) << 3))] =
        *(const uint4*)&s[(size_t)(p0 + i2) * Q + q0 + sg * 8];
  }
  __syncthreads();
  int j = tid >> 2, ms = tid & 3;
  u16 vals[16];
#pragma unroll
  for (int ii = 0; ii < 16; ++ii) {
    int row = ms * 16 + ii;
    vals[ii] = tile[row * 72 + (j ^ (((row >> 3) & 7) << 3))];
  }
  uint4 o0, o1;
  o0.x = (u32)vals[0] | ((u32)vals[1] << 16);
  o0.y = (u32)vals[2] | ((u32)vals[3] << 16);
  o0.z = (u32)vals[4] | ((u32)vals[5] << 16);
  o0.w = (u32)vals[6] | ((u32)vals[7] << 16);
  o1.x = (u32)vals[8] | ((u32)vals[9] << 16);
  o1.y = (u32)vals[10] | ((u32)vals[11] << 16);
  o1.z = (u32)vals[12] | ((u32)vals[13] << 16);
  o1.w = (u32)vals[14] | ((u32)vals[15] << 16);
  size_t drow = (size_t)(q0 + j) * P + p0 + ms * 16;
  *(uint4*)&d[drow] = o0;
  *(uint4*)&d[drow + 8] = o1;
}

// ---------------- axial attention pass-pair on 64x64 slabs ----------------
__global__ __launch_bounds__(256, 2) void attn_pair(const u16* __restrict__ q,
    const u16* __restrict__ k, const u16* __restrict__ v, u16* __restrict__ dst,
    int uStride, int sMul) {
  __shared__ __align__(16) u16 sm[6 * 4096];
  u16* LQ = sm;             u16* LK = sm + 4096;      u16* LV = sm + 2 * 4096;
  u16* LQT = sm + 3 * 4096; u16* LKT = sm + 4 * 4096; u16* LVT = sm + 5 * 4096;
  u16* A1 = LK;   // aliases: K buffers dead after score phase (barrier-protected)
  u16* A2 = LKT;
  int tid = threadIdx.x;
  int id = blockIdx.x;
  int bc = id >> 6, sidx = id & 63;
  size_t base = (size_t)bc * VOL + (size_t)sidx * sMul;
  int wave = tid >> 6, lane = tid & 63, r = lane & 15, g = lane >> 4;
  int pairid = tid >> 3, seg = tid & 7;
  int u0 = pairid * 2;
  const u16* srcs[3] = {q, k, v};
  u16* Ln_[3] = {LQ, LK, LV};
  u16* Lt_[3] = {LQT, LKT, LVT};
#pragma unroll
  for (int t3 = 0; t3 < 3; ++t3) {
    const u16* p = srcs[t3] + base + (size_t)u0 * uStride + seg * 8;
    uint4 ra = *(const uint4*)p;
    uint4 rb = *(const uint4*)(p + uStride);
    *(uint4*)&Ln_[t3][swA(u0, seg * 8)] = ra;
    *(uint4*)&Ln_[t3][swA(u0 + 1, seg * 8)] = rb;
    union { uint4 vv; u16 ss[8]; } Ua, Ub;
    Ua.vv = ra; Ub.vv = rb;
#pragma unroll
    for (int vi = 0; vi < 8; ++vi) {
      int vvx = seg * 8 + vi;
      *(u32*)&Lt_[t3][swA(vvx, u0)] = (u32)Ua.ss[vi] | ((u32)Ub.ss[vi] << 16);
    }
  }
  __syncthreads();
  int row0 = wave * 16;
  f32x4 s1[4], s2[4];
#pragma unroll
  for (int nf = 0; nf < 4; ++nf)
#pragma unroll
    for (int e = 0; e < 4; ++e) { s1[nf][e] = 0.f; s2[nf][e] = 0.f; }
#pragma unroll
  for (int ks = 0; ks < 2; ++ks) {
    int cb = ks * 32 + g * 8;
    bf16x8 aK = ldsfrag(&LK[swA(row0 + r, cb)]);
    bf16x8 aKT = ldsfrag(&LKT[swA(row0 + r, cb)]);
#pragma unroll
    for (int nf = 0; nf < 4; ++nf) {
      bf16x8 bQ = ldsfrag(&LQ[swA(nf * 16 + r, cb)]);
      bf16x8 bQT = ldsfrag(&LQT[swA(nf * 16 + r, cb)]);
      s1[nf] = __builtin_amdgcn_mfma_f32_16x16x32_bf16(aK, bQ, s1[nf], 0, 0, 0);
      s2[nf] = __builtin_amdgcn_mfma_f32_16x16x32_bf16(aKT, bQT, s2[nf], 0, 0, 0);
    }
  }
  __syncthreads();  // all waves done reading LK/LKT before A1/A2 overwrite them
#pragma unroll
  for (int m2 = 0; m2 < 2; ++m2) {
    f32x4* ss = m2 ? s2 : s1;
    u16* Adst = m2 ? A2 : A1;
#pragma unroll
    for (int jj = 0; jj < 4; ++jj) {
      float mx = fmaxf(fmaxf(ss[0][jj], ss[1][jj]), fmaxf(ss[2][jj], ss[3][jj]));
      mx = fmaxf(mx, __shfl_xor(mx, 1, 64));
      mx = fmaxf(mx, __shfl_xor(mx, 2, 64));
      mx = fmaxf(mx, __shfl_xor(mx, 4, 64));
      mx = fmaxf(mx, __shfl_xor(mx, 8, 64));
      float p0 = __expf((ss[0][jj] - mx) * 0.125f);
      float p1 = __expf((ss[1][jj] - mx) * 0.125f);
      float p2 = __expf((ss[2][jj] - mx) * 0.125f);
      float p3 = __expf((ss[3][jj] - mx) * 0.125f);
      float sum = p0 + p1 + p2 + p3;
      sum += __shfl_xor(sum, 1, 64);
      sum += __shfl_xor(sum, 2, 64);
      sum += __shfl_xor(sum, 4, 64);
      sum += __shfl_xor(sum, 8, 64);
      float inv = 1.0f / sum;
      ss[0][jj] = p0 * inv; ss[1][jj] = p1 * inv; ss[2][jj] = p2 * inv; ss[3][jj] = p3 * inv;
    }
    int j0 = row0 + g * 4;
#pragma unroll
    for (int nf = 0; nf < 4; ++nf) {
      int i = nf * 16 + r;
      int a0 = swA(i, j0);
      *(u32*)&Adst[a0]     = (u32)f2bf(ss[nf][0]) | ((u32)f2bf(ss[nf][1]) << 16);
      *(u32*)&Adst[a0 + 2] = (u32)f2bf(ss[nf][2]) | ((u32)f2bf(ss[nf][3]) << 16);
    }
  }
  __syncthreads();
  f32x4 o[4];
#pragma unroll
  for (int nf = 0; nf < 4; ++nf)
#pragma unroll
    for (int e = 0; e < 4; ++e) o[nf][e] = 0.f;
#pragma unroll
  for (int ks = 0; ks < 2; ++ks) {
    int cb = ks * 32 + g * 8;
    bf16x8 aA = ldsfrag(&A1[swA(row0 + r, cb)]);
    bf16x8 aV = ldsfrag(&LV[swA(row0 + r, cb)]);
#pragma unroll
    for (int nf = 0; nf < 4; ++nf) {
      bf16x8 bVT = ldsfrag(&LVT[swA(nf * 16 + r, cb)]);
      bf16x8 bA2 = ldsfrag(&A2[swA(nf * 16 + r, cb)]);
      o[nf] = __builtin_amdgcn_mfma_f32_16x16x32_bf16(aA, bVT, o[nf], 0, 0, 0);
      o[nf] = __builtin_amdgcn_mfma_f32_16x16x32_bf16(aV, bA2, o[nf], 0, 0, 0);
    }
  }
#pragma unroll
  for (int nf = 0; nf < 4; ++nf) {
    int vv = nf * 16 + r;
#pragma unroll
    for (int jj = 0; jj < 4; ++jj) {
      int u = row0 + g * 4 + jj;
      dst[base + (size_t)u * uStride + vv] = f2bf(o[nf][jj] * 0.5f);
    }
  }
}

// ---------------- final conv3d (cin=192 cat, cout=64) + BN + ReLU + BN + residual q ----------------
// Per-tensor 64-channel staging (pitch-72 XOR layout, same as conv_qkv). 9 phases (3dh x 3t),
// 18 unrolled k-steps each. BM=256 = 4w x 64d; 8 waves = 4 mw x 2 nw.
__global__ __launch_bounds__(512, 2) void conv_final(const u16* __restrict__ AVa,
    const u16* __restrict__ AVb, const u16* __restrict__ AVc, const u16* __restrict__ BCw,
    const float* __restrict__ bcb, const u16* __restrict__ qb, float* __restrict__ out) {
  __shared__ __align__(16) u16 xT[6 * 66 * 72];  // [wwi 0..5][dpos 0..65][cin64 swizzled]
  int tid = threadIdx.x;
  int id = blockIdx.x;
  int lin = (id & 7) * 256 + (id >> 3);  // 2048 = 8*256
  int b = lin >> 10, h = (lin >> 4) & 63, w0 = (lin & 15) * 4;
  int wave = tid >> 6, lane = tid & 63, r = lane & 15, g = lane >> 4;
  int mw = wave >> 1, nw = wave & 1;
  int pairid = tid >> 3, seg = tid & 7;
  if (tid < 384) {  // zero d-pad rows (dpos 0 and 65); swizzle identity there
    int wwi = tid >> 6, ci = tid & 63;
    xT[(wwi * 66 + 0) * 72 + ci] = 0;
    xT[(wwi * 66 + 65) * 72 + ci] = 0;
  }
  f32x4 acc[4][2];
#pragma unroll
  for (int i = 0; i < 4; ++i)
#pragma unroll
    for (int j = 0; j < 2; ++j)
#pragma unroll
      for (int e = 0; e < 4; ++e) acc[i][j][e] = 0.f;

  for (int dh = 0; dh < 3; ++dh) {
    int hh = h + dh - 1;
    if ((unsigned)hh >= 64u) continue;
    for (int t = 0; t < 3; ++t) {
      const u16* sp = (t == 0) ? AVa : ((t == 1) ? AVb : AVc);
      __syncthreads();
#pragma unroll
      for (int pi = 0; pi < 3; ++pi) {
        int pair = pairid + 64 * pi;  // [0,192): wwi(6) x cin-pair(32)
        int wwi = pair >> 5, cin0 = (pair & 31) * 2;
        int ww = w0 + wwi - 1;
        uint4 ra{}, rb{};
        if ((unsigned)ww < 64u) {
          const u16* p = sp + (size_t)(b * 64 + cin0) * VOL + hh * 4096 + ww * 64 + seg * 8;
          ra = *(const uint4*)p;
          rb = *(const uint4*)(p + VOL);
        }
        union { uint4 vv; u16 ss[8]; } Ua, Ub;
        Ua.vv = ra; Ub.vv = rb;
        int rowb = wwi * 66;
#pragma unroll
        for (int di = 0; di < 8; ++di) {
          int dpos = seg * 8 + di + 1;
          *(u32*)&xT[(rowb + dpos) * 72 + (cin0 ^ (((dpos >> 3) & 7) << 3))] =
              (u32)Ua.ss[di] | ((u32)Ub.ss[di] << 16);
        }
      }
      __syncthreads();
#pragma unroll
      for (int sub = 0; sub < 18; ++sub) {
        int dw = sub / 6, dd = (sub >> 1) % 3, c32 = sub & 1;  // constants after unroll
        int colb = c32 * 32 + g * 8;
        int wwi = mw + dw;
        bf16x8 A[4];
#pragma unroll
        for (int dq = 0; dq < 4; ++dq) {
          int dpos = dq * 16 + r + dd;
          A[dq] = ldsfrag(&xT[(wwi * 66 + dpos) * 72 + (colb ^ (((dpos >> 3) & 7) << 3))]);
        }
        const u16* Bp = BCw + ((size_t)((((dh * 3 + t) * 18 + sub) * 4) + nw * 2) * 64 + lane) * 8;
#pragma unroll
        for (int nf = 0; nf < 2; ++nf) {
          bf16x8 Bf = *(const bf16x8*)(Bp + nf * 512);
#pragma unroll
          for (int dq = 0; dq < 4; ++dq)
            acc[dq][nf] = __builtin_amdgcn_mfma_f32_16x16x32_bf16(A[dq], Bf, acc[dq][nf], 0, 0, 0);
        }
      }
    }
  }
  const float S = 0.9999950000374997f;  // 1/sqrt(1+1e-5)
#pragma unroll
  for (int nf = 0; nf < 2; ++nf) {
    int cout = (nw * 2 + nf) * 16 + r;
    float bsv = bcb[cout];
#pragma unroll
    for (int dq = 0; dq < 4; ++dq) {
      int d0 = dq * 16 + g * 4;
      int idx = (b * 64 + cout) * VOL + h * 4096 + (w0 + mw) * 64 + d0;
      u16x4 qv = *(const u16x4*)(qb + idx);
      float4 ov;
      float t0 = (acc[dq][nf][0] + bsv) * S; t0 = t0 > 0.f ? t0 : 0.f; ov.x = t0 * S + bf2f(qv[0]);
      float t1 = (acc[dq][nf][1] + bsv) * S; t1 = t1 > 0.f ? t1 : 0.f; ov.y = t1 * S + bf2f(qv[1]);
      float t2 = (acc[dq][nf][2] + bsv) * S; t2 = t2 > 0.f ? t2 : 0.f; ov.z = t2 * S + bf2f(qv[2]);
      float t3 = (acc[dq][nf][3] + bsv) * S; t3 = t3 > 0.f ? t3 : 0.f; ov.w = t3 * S + bf2f(qv[3]);
      *(float4*)(out + idx) = ov;
    }
  }
}

extern "C" void kernel_launch(void* const* d_in, const int* in_sizes, int n_in,
                              void* d_out, int out_size, void* d_ws, size_t ws_size,
                              hipStream_t stream) {
  const float* x  = (const float*)d_in[0];
  const float* Wq = (const float*)d_in[1];
  const float* bq = (const float*)d_in[2];
  const float* Wk = (const float*)d_in[3];
  const float* bk = (const float*)d_in[4];
  const float* Wv = (const float*)d_in[5];
  const float* bv = (const float*)d_in[6];
  const float* Wc = (const float*)d_in[7];
  const float* bc = (const float*)d_in[8];
  float* out = (float*)d_out;
  u16* ws = (u16*)d_ws;
  const size_t T = (size_t)33554432;
  u16* qb = ws;
  u16* kb = ws + T;
  u16* vb = ws + 2 * T;
  u16* qT = ws + 3 * T;
  u16* kT = ws + 4 * T;
  u16* vT = ws + 5 * T;
  u16* avaT = ws + 6 * T;
  u16* BQ = ws + 7 * T;
  u16* BC = BQ + 331776;
  u16* AVa = qT;
  u16* AVb = kT;
  u16* AVc = vT;

  swz_qkv<<<1296, 256, 0, stream>>>(Wq, Wk, Wv, BQ);
  swz_c<<<1296, 256, 0, stream>>>(Wc, BC);
  conv_qkv<<<4096, 512, 0, stream>>>(x, BQ, bq, bk, bv, qb, kb, vb);
  ktranspose<<<8192, 256, 0, stream>>>(qb, qT, 4096, 64);
  ktranspose<<<8192, 256, 0, stream>>>(kb, kT, 4096, 64);
  ktranspose<<<8192, 256, 0, stream>>>(vb, vT, 4096, 64);
  attn_pair<<<8192, 256, 0, stream>>>(qT, kT, vT, avaT, 64, 4096);
  ktranspose<<<8192, 256, 0, stream>>>(avaT, AVa, 64, 4096);
  attn_pair<<<8192, 256, 0, stream>>>(qb, kb, vb, AVb, 4096, 64);
  attn_pair<<<8192, 256, 0, stream>>>(qb, kb, vb, AVc, 64, 4096);
  conv_final<<<2048, 512, 0, stream>>>(AVa, AVb, AVc, BC, bc, qb, out);
}

// Round 5
// 1396.011 us; speedup vs baseline: 1.0944x; 1.0944x over previous
//
#include <hip/hip_runtime.h>

typedef unsigned short u16;
typedef unsigned int u32;
typedef __attribute__((ext_vector_type(8))) __bf16 bf16x8;
typedef __attribute__((ext_vector_type(4))) float f32x4;
typedef __attribute__((ext_vector_type(4))) u16 u16x4;

#define VOL 262144  // 64^3

__device__ __forceinline__ u16 f2bf(float f) {
  u32 u = __builtin_bit_cast(u32, f);
  u32 r = u + 0x7FFFu + ((u >> 16) & 1u);
  return (u16)(r >> 16);
}
__device__ __forceinline__ float bf2f(u16 h) {
  return __builtin_bit_cast(float, ((u32)h) << 16);
}
__device__ __forceinline__ bf16x8 ldsfrag(const u16* p) { return *(const bf16x8*)p; }

// pitch-64 XOR swizzle for attn buffers.
__device__ __forceinline__ int swA(int row, int col) {
  return row * 64 + (col ^ (((row ^ (row >> 3)) & 7) << 3));
}

// ---------------- weight pre-swizzle: Wq/Wk/Wv -> per-lane B-fragment order ----------------
// K order (s in [0,54)): dh(3) / dw(3) / dd(3) / c32(2).  nf in [0,12): cout group of 16.
__global__ __launch_bounds__(256) void swz_qkv(const float* __restrict__ Wq,
    const float* __restrict__ Wk, const float* __restrict__ Wv, u16* __restrict__ out) {
  int idx = blockIdx.x * 256 + threadIdx.x;
  if (idx >= 54 * 12 * 64 * 8) return;
  int jj = idx & 7;
  int lane = (idx >> 3) & 63;
  int t = idx >> 9;
  int nf = t % 12, s = t / 12;
  int dh = s / 18, sub = s % 18;
  int dw = sub / 6, dd = (sub >> 1) % 3, c32 = sub & 1;
  int coutg = nf * 16 + (lane & 15);
  int cin = c32 * 32 + (lane >> 4) * 8 + jj;
  const float* W = (coutg < 64) ? Wq : ((coutg < 128) ? Wk : Wv);
  int c = coutg & 63;
  out[idx] = f2bf(W[(c * 64 + cin) * 27 + dh * 9 + dw * 3 + dd]);
}

// K order (s in [0,162)): dh(3) / t(3: AVa,AVb,AVc 64-ch block) / dw(3) / dd(3) / c32(2)
__global__ __launch_bounds__(256) void swz_c(const float* __restrict__ Wc, u16* __restrict__ out) {
  int idx = blockIdx.x * 256 + threadIdx.x;
  if (idx >= 162 * 4 * 64 * 8) return;
  int jj = idx & 7;
  int lane = (idx >> 3) & 63;
  int nf = (idx >> 9) & 3;
  int s = idx >> 11;
  int dh = s / 54, rem = s % 54;
  int t = rem / 18, sub = rem % 18;
  int dw = sub / 6, dd = (sub >> 1) % 3, c32 = sub & 1;
  int cout = nf * 16 + (lane & 15);
  int cin = t * 64 + c32 * 32 + (lane >> 4) * 8 + jj;
  out[idx] = f2bf(Wc[(cout * 192 + cin) * 27 + dh * 9 + dw * 3 + dd]);
}

// ---------------- fused q/k/v conv3d (implicit GEMM, BM=128 = 2w x 64d, N=192, 8 waves) ----------------
// Runtime dw loop + unrolled dd/c32 (6-step body). NO full unroll (round-4 regression) and
// NO forced reg cap (round-2 spill). LDS fragment offsets precomputed in P[][][] (static idx).
__global__ __launch_bounds__(512, 2) void conv_qkv(const float* __restrict__ x,
    const u16* __restrict__ BQ, const float* __restrict__ bq, const float* __restrict__ bk,
    const float* __restrict__ bv, u16* __restrict__ qb, u16* __restrict__ kb,
    u16* __restrict__ vb) {
  __shared__ __align__(16) u16 xT[4 * 66 * 72];  // [wwi][dpos 0..65][cin swizzled], pitch 72
  int tid = threadIdx.x;
  int id = blockIdx.x;
  int lin = (id & 7) * 512 + (id >> 3);  // XCD-chunk swizzle (4096 = 8*512)
  int b = lin >> 11, h = (lin >> 5) & 63, w0 = (lin & 31) * 2;
  int wave = tid >> 6, lane = tid & 63, r = lane & 15, g = lane >> 4;
  int mhalf = wave >> 2, nq = wave & 3;
  int pairid = tid >> 3, seg = tid & 7;
  if (tid < 256) {  // zero d-pad rows (dpos 0 and 65); swizzle identity there
    int wwi = tid >> 6, ci = tid & 63;
    xT[(wwi * 66 + 0) * 72 + ci] = 0;
    xT[(wwi * 66 + 65) * 72 + ci] = 0;
  }
  u32 P[4][3][2];  // LDS elem offsets per (m-frag l, dd, c32); +wwi*4752 at use
#pragma unroll
  for (int l = 0; l < 4; ++l)
#pragma unroll
    for (int dd = 0; dd < 3; ++dd)
#pragma unroll
      for (int c32 = 0; c32 < 2; ++c32) {
        int dpos = l * 16 + r + dd;
        P[l][dd][c32] = dpos * 72 + ((c32 * 32 + g * 8) ^ (((dpos >> 3) & 7) << 3));
      }
  f32x4 acc[4][3];
#pragma unroll
  for (int i = 0; i < 4; ++i)
#pragma unroll
    for (int j = 0; j < 3; ++j)
#pragma unroll
      for (int e = 0; e < 4; ++e) acc[i][j][e] = 0.0f;

  for (int dh = 0; dh < 3; ++dh) {
    int hh = h + dh - 1;
    if ((unsigned)hh >= 64u) continue;
    __syncthreads();
#pragma unroll
    for (int pi = 0; pi < 2; ++pi) {
      int pair = pairid + 64 * pi;  // [0,128): wwi(4) x cin-pair(32)
      int wwi = pair >> 5, cin0 = (pair & 31) * 2;
      int ww = w0 + wwi - 1;
      float4 a0{}, a1{}, b0{}, b1{};
      if ((unsigned)ww < 64u) {
        const float* p = x + (size_t)(b * 64 + cin0) * VOL + hh * 4096 + ww * 64 + seg * 8;
        a0 = *(const float4*)p;        a1 = *(const float4*)(p + 4);
        b0 = *(const float4*)(p + VOL); b1 = *(const float4*)(p + VOL + 4);
      }
      u16 ua[8], ub[8];
      ua[0]=f2bf(a0.x); ua[1]=f2bf(a0.y); ua[2]=f2bf(a0.z); ua[3]=f2bf(a0.w);
      ua[4]=f2bf(a1.x); ua[5]=f2bf(a1.y); ua[6]=f2bf(a1.z); ua[7]=f2bf(a1.w);
      ub[0]=f2bf(b0.x); ub[1]=f2bf(b0.y); ub[2]=f2bf(b0.z); ub[3]=f2bf(b0.w);
      ub[4]=f2bf(b1.x); ub[5]=f2bf(b1.y); ub[6]=f2bf(b1.z); ub[7]=f2bf(b1.w);
      int rowb = wwi * 66;
#pragma unroll
      for (int di = 0; di < 8; ++di) {
        int dpos = seg * 8 + di + 1;
        *(u32*)&xT[(rowb + dpos) * 72 + (cin0 ^ (((dpos >> 3) & 7) << 3))] =
            (u32)ua[di] | ((u32)ub[di] << 16);
      }
    }
    __syncthreads();
    const u16* Bp = BQ + ((size_t)(dh * 18) * 12 + nq * 3) * 512 + (size_t)lane * 8;
    for (int dw = 0; dw < 3; ++dw) {
      int wwiE = (mhalf + dw) * 4752;  // 66*72
#pragma unroll
      for (int dd = 0; dd < 3; ++dd) {
#pragma unroll
        for (int c32 = 0; c32 < 2; ++c32) {
          bf16x8 A[4];
#pragma unroll
          for (int l = 0; l < 4; ++l) A[l] = ldsfrag(&xT[wwiE + P[l][dd][c32]]);
#pragma unroll
          for (int nf = 0; nf < 3; ++nf) {
            bf16x8 Bf = *(const bf16x8*)(Bp + nf * 512);
#pragma unroll
            for (int l = 0; l < 4; ++l)
              acc[l][nf] = __builtin_amdgcn_mfma_f32_16x16x32_bf16(A[l], Bf, acc[l][nf], 0, 0, 0);
          }
          Bp += 12 * 512;  // next k-step
        }
      }
    }
  }
#pragma unroll
  for (int nf = 0; nf < 3; ++nf) {
    int coutg = (nq * 3 + nf) * 16 + r;
    int ten = coutg >> 6, c = coutg & 63;
    u16* dst = (ten == 0) ? qb : ((ten == 1) ? kb : vb);
    const float* bias = (ten == 0) ? bq : ((ten == 1) ? bk : bv);
    float bsv = bias[c];
#pragma unroll
    for (int l = 0; l < 4; ++l) {
      int d0 = l * 16 + g * 4;
      int idx = (b * 64 + c) * VOL + h * 4096 + (w0 + mhalf) * 64 + d0;
      u16x4 o;
#pragma unroll
      for (int jj = 0; jj < 4; ++jj) o[jj] = f2bf(acc[l][nf][jj] + bsv);
      *(u16x4*)(dst + idx) = o;
    }
  }
}

// ---------------- tiled transpose within each (b,c) volume: src[P][Q] -> dst[Q][P] ----------------
__global__ __launch_bounds__(256, 6) void ktranspose(const u16* __restrict__ src,
    u16* __restrict__ dst, int P, int Q) {
  __shared__ __align__(16) u16 tile[64 * 72];
  int tid = threadIdx.x;
  int id = blockIdx.x;
  int bc = id >> 6, t = id & 63;
  int qt = Q >> 6;
  int p0 = (t / qt) * 64, q0 = (t % qt) * 64;
  const u16* s = src + (size_t)bc * VOL;
  u16* d = dst + (size_t)bc * VOL;
#pragma unroll
  for (int it = 0; it < 2; ++it) {
    int c = tid + 256 * it;
    int i2 = c >> 3, sg = c & 7;
    *(uint4*)&tile[i2 * 72 + ((sg * 8) ^ (((i2 >> 3) & 7) << 3))] =
        *(const uint4*)&s[(size_t)(p0 + i2) * Q + q0 + sg * 8];
  }
  __syncthreads();
  int j = tid >> 2, ms = tid & 3;
  u16 vals[16];
#pragma unroll
  for (int ii = 0; ii < 16; ++ii) {
    int row = ms * 16 + ii;
    vals[ii] = tile[row * 72 + (j ^ (((row >> 3) & 7) << 3))];
  }
  uint4 o0, o1;
  o0.x = (u32)vals[0] | ((u32)vals[1] << 16);
  o0.y = (u32)vals[2] | ((u32)vals[3] << 16);
  o0.z = (u32)vals[4] | ((u32)vals[5] << 16);
  o0.w = (u32)vals[6] | ((u32)vals[7] << 16);
  o1.x = (u32)vals[8] | ((u32)vals[9] << 16);
  o1.y = (u32)vals[10] | ((u32)vals[11] << 16);
  o1.z = (u32)vals[12] | ((u32)vals[13] << 16);
  o1.w = (u32)vals[14] | ((u32)vals[15] << 16);
  size_t drow = (size_t)(q0 + j) * P + p0 + ms * 16;
  *(uint4*)&d[drow] = o0;
  *(uint4*)&d[drow + 8] = o1;
}

// ---------------- axial attention pass-pair on 64x64 slabs ----------------
__global__ __launch_bounds__(256, 2) void attn_pair(const u16* __restrict__ q,
    const u16* __restrict__ k, const u16* __restrict__ v, u16* __restrict__ dst,
    int uStride, int sMul) {
  __shared__ __align__(16) u16 sm[6 * 4096];
  u16* LQ = sm;             u16* LK = sm + 4096;      u16* LV = sm + 2 * 4096;
  u16* LQT = sm + 3 * 4096; u16* LKT = sm + 4 * 4096; u16* LVT = sm + 5 * 4096;
  u16* A1 = LK;   // aliases: K buffers dead after score phase (barrier-protected)
  u16* A2 = LKT;
  int tid = threadIdx.x;
  int id = blockIdx.x;
  int bc = id >> 6, sidx = id & 63;
  size_t base = (size_t)bc * VOL + (size_t)sidx * sMul;
  int wave = tid >> 6, lane = tid & 63, r = lane & 15, g = lane >> 4;
  int pairid = tid >> 3, seg = tid & 7;
  int u0 = pairid * 2;
  const u16* srcs[3] = {q, k, v};
  u16* Ln_[3] = {LQ, LK, LV};
  u16* Lt_[3] = {LQT, LKT, LVT};
#pragma unroll
  for (int t3 = 0; t3 < 3; ++t3) {
    const u16* p = srcs[t3] + base + (size_t)u0 * uStride + seg * 8;
    uint4 ra = *(const uint4*)p;
    uint4 rb = *(const uint4*)(p + uStride);
    *(uint4*)&Ln_[t3][swA(u0, seg * 8)] = ra;
    *(uint4*)&Ln_[t3][swA(u0 + 1, seg * 8)] = rb;
    union { uint4 vv; u16 ss[8]; } Ua, Ub;
    Ua.vv = ra; Ub.vv = rb;
#pragma unroll
    for (int vi = 0; vi < 8; ++vi) {
      int vvx = seg * 8 + vi;
      *(u32*)&Lt_[t3][swA(vvx, u0)] = (u32)Ua.ss[vi] | ((u32)Ub.ss[vi] << 16);
    }
  }
  __syncthreads();
  int row0 = wave * 16;
  f32x4 s1[4], s2[4];
#pragma unroll
  for (int nf = 0; nf < 4; ++nf)
#pragma unroll
    for (int e = 0; e < 4; ++e) { s1[nf][e] = 0.f; s2[nf][e] = 0.f; }
#pragma unroll
  for (int ks = 0; ks < 2; ++ks) {
    int cb = ks * 32 + g * 8;
    bf16x8 aK = ldsfrag(&LK[swA(row0 + r, cb)]);
    bf16x8 aKT = ldsfrag(&LKT[swA(row0 + r, cb)]);
#pragma unroll
    for (int nf = 0; nf < 4; ++nf) {
      bf16x8 bQ = ldsfrag(&LQ[swA(nf * 16 + r, cb)]);
      bf16x8 bQT = ldsfrag(&LQT[swA(nf * 16 + r, cb)]);
      s1[nf] = __builtin_amdgcn_mfma_f32_16x16x32_bf16(aK, bQ, s1[nf], 0, 0, 0);
      s2[nf] = __builtin_amdgcn_mfma_f32_16x16x32_bf16(aKT, bQT, s2[nf], 0, 0, 0);
    }
  }
  __syncthreads();  // all waves done reading LK/LKT before A1/A2 overwrite them
#pragma unroll
  for (int m2 = 0; m2 < 2; ++m2) {
    f32x4* ss = m2 ? s2 : s1;
    u16* Adst = m2 ? A2 : A1;
#pragma unroll
    for (int jj = 0; jj < 4; ++jj) {
      float mx = fmaxf(fmaxf(ss[0][jj], ss[1][jj]), fmaxf(ss[2][jj], ss[3][jj]));
      mx = fmaxf(mx, __shfl_xor(mx, 1, 64));
      mx = fmaxf(mx, __shfl_xor(mx, 2, 64));
      mx = fmaxf(mx, __shfl_xor(mx, 4, 64));
      mx = fmaxf(mx, __shfl_xor(mx, 8, 64));
      float p0 = __expf((ss[0][jj] - mx) * 0.125f);
      float p1 = __expf((ss[1][jj] - mx) * 0.125f);
      float p2 = __expf((ss[2][jj] - mx) * 0.125f);
      float p3 = __expf((ss[3][jj] - mx) * 0.125f);
      float sum = p0 + p1 + p2 + p3;
      sum += __shfl_xor(sum, 1, 64);
      sum += __shfl_xor(sum, 2, 64);
      sum += __shfl_xor(sum, 4, 64);
      sum += __shfl_xor(sum, 8, 64);
      float inv = 1.0f / sum;
      ss[0][jj] = p0 * inv; ss[1][jj] = p1 * inv; ss[2][jj] = p2 * inv; ss[3][jj] = p3 * inv;
    }
    int j0 = row0 + g * 4;
#pragma unroll
    for (int nf = 0; nf < 4; ++nf) {
      int i = nf * 16 + r;
      int a0 = swA(i, j0);
      *(u32*)&Adst[a0]     = (u32)f2bf(ss[nf][0]) | ((u32)f2bf(ss[nf][1]) << 16);
      *(u32*)&Adst[a0 + 2] = (u32)f2bf(ss[nf][2]) | ((u32)f2bf(ss[nf][3]) << 16);
    }
  }
  __syncthreads();
  f32x4 o[4];
#pragma unroll
  for (int nf = 0; nf < 4; ++nf)
#pragma unroll
    for (int e = 0; e < 4; ++e) o[nf][e] = 0.f;
#pragma unroll
  for (int ks = 0; ks < 2; ++ks) {
    int cb = ks * 32 + g * 8;
    bf16x8 aA = ldsfrag(&A1[swA(row0 + r, cb)]);
    bf16x8 aV = ldsfrag(&LV[swA(row0 + r, cb)]);
#pragma unroll
    for (int nf = 0; nf < 4; ++nf) {
      bf16x8 bVT = ldsfrag(&LVT[swA(nf * 16 + r, cb)]);
      bf16x8 bA2 = ldsfrag(&A2[swA(nf * 16 + r, cb)]);
      o[nf] = __builtin_amdgcn_mfma_f32_16x16x32_bf16(aA, bVT, o[nf], 0, 0, 0);
      o[nf] = __builtin_amdgcn_mfma_f32_16x16x32_bf16(aV, bA2, o[nf], 0, 0, 0);
    }
  }
#pragma unroll
  for (int nf = 0; nf < 4; ++nf) {
    int vv = nf * 16 + r;
#pragma unroll
    for (int jj = 0; jj < 4; ++jj) {
      int u = row0 + g * 4 + jj;
      dst[base + (size_t)u * uStride + vv] = f2bf(o[nf][jj] * 0.5f);
    }
  }
}

// ---------------- final conv3d (cin=192 cat, cout=64) + BN + ReLU + BN + residual q ----------------
// 9 phases (3dh x 3t), per-tensor 64-ch pitch-72 staging; runtime dw + unrolled dd/c32 k-loop.
__global__ __launch_bounds__(512, 2) void conv_final(const u16* __restrict__ AVa,
    const u16* __restrict__ AVb, const u16* __restrict__ AVc, const u16* __restrict__ BCw,
    const float* __restrict__ bcb, const u16* __restrict__ qb, float* __restrict__ out) {
  __shared__ __align__(16) u16 xT[6 * 66 * 72];  // [wwi 0..5][dpos 0..65][cin64 swizzled]
  int tid = threadIdx.x;
  int id = blockIdx.x;
  int lin = (id & 7) * 256 + (id >> 3);  // 2048 = 8*256
  int b = lin >> 10, h = (lin >> 4) & 63, w0 = (lin & 15) * 4;
  int wave = tid >> 6, lane = tid & 63, r = lane & 15, g = lane >> 4;
  int mw = wave >> 1, nw = wave & 1;
  int pairid = tid >> 3, seg = tid & 7;
  if (tid < 384) {  // zero d-pad rows (dpos 0 and 65); swizzle identity there
    int wwi = tid >> 6, ci = tid & 63;
    xT[(wwi * 66 + 0) * 72 + ci] = 0;
    xT[(wwi * 66 + 65) * 72 + ci] = 0;
  }
  u32 P[4][3][2];
#pragma unroll
  for (int dq = 0; dq < 4; ++dq)
#pragma unroll
    for (int dd = 0; dd < 3; ++dd)
#pragma unroll
      for (int c32 = 0; c32 < 2; ++c32) {
        int dpos = dq * 16 + r + dd;
        P[dq][dd][c32] = dpos * 72 + ((c32 * 32 + g * 8) ^ (((dpos >> 3) & 7) << 3));
      }
  f32x4 acc[4][2];
#pragma unroll
  for (int i = 0; i < 4; ++i)
#pragma unroll
    for (int j = 0; j < 2; ++j)
#pragma unroll
      for (int e = 0; e < 4; ++e) acc[i][j][e] = 0.f;

  for (int dh = 0; dh < 3; ++dh) {
    int hh = h + dh - 1;
    if ((unsigned)hh >= 64u) continue;
    for (int t = 0; t < 3; ++t) {
      const u16* sp = (t == 0) ? AVa : ((t == 1) ? AVb : AVc);
      __syncthreads();
#pragma unroll
      for (int pi = 0; pi < 3; ++pi) {
        int pair = pairid + 64 * pi;  // [0,192): wwi(6) x cin-pair(32)
        int wwi = pair >> 5, cin0 = (pair & 31) * 2;
        int ww = w0 + wwi - 1;
        uint4 ra{}, rb{};
        if ((unsigned)ww < 64u) {
          const u16* p = sp + (size_t)(b * 64 + cin0) * VOL + hh * 4096 + ww * 64 + seg * 8;
          ra = *(const uint4*)p;
          rb = *(const uint4*)(p + VOL);
        }
        union { uint4 vv; u16 ss[8]; } Ua, Ub;
        Ua.vv = ra; Ub.vv = rb;
        int rowb = wwi * 66;
#pragma unroll
        for (int di = 0; di < 8; ++di) {
          int dpos = seg * 8 + di + 1;
          *(u32*)&xT[(rowb + dpos) * 72 + (cin0 ^ (((dpos >> 3) & 7) << 3))] =
              (u32)Ua.ss[di] | ((u32)Ub.ss[di] << 16);
        }
      }
      __syncthreads();
      const u16* Bp = BCw + ((size_t)((dh * 3 + t) * 18) * 4 + nw * 2) * 512 + (size_t)lane * 8;
      for (int dw = 0; dw < 3; ++dw) {
        int wwiE = (mw + dw) * 4752;  // 66*72
#pragma unroll
        for (int dd = 0; dd < 3; ++dd) {
#pragma unroll
          for (int c32 = 0; c32 < 2; ++c32) {
            bf16x8 A[4];
#pragma unroll
            for (int dq = 0; dq < 4; ++dq) A[dq] = ldsfrag(&xT[wwiE + P[dq][dd][c32]]);
#pragma unroll
            for (int nf = 0; nf < 2; ++nf) {
              bf16x8 Bf = *(const bf16x8*)(Bp + nf * 512);
#pragma unroll
              for (int dq = 0; dq < 4; ++dq)
                acc[dq][nf] = __builtin_amdgcn_mfma_f32_16x16x32_bf16(A[dq], Bf, acc[dq][nf], 0, 0, 0);
            }
            Bp += 4 * 512;  // next k-step
          }
        }
      }
    }
  }
  const float S = 0.9999950000374997f;  // 1/sqrt(1+1e-5)
#pragma unroll
  for (int nf = 0; nf < 2; ++nf) {
    int cout = (nw * 2 + nf) * 16 + r;
    float bsv = bcb[cout];
#pragma unroll
    for (int dq = 0; dq < 4; ++dq) {
      int d0 = dq * 16 + g * 4;
      int idx = (b * 64 + cout) * VOL + h * 4096 + (w0 + mw) * 64 + d0;
      u16x4 qv = *(const u16x4*)(qb + idx);
      float4 ov;
      float t0 = (acc[dq][nf][0] + bsv) * S; t0 = t0 > 0.f ? t0 : 0.f; ov.x = t0 * S + bf2f(qv[0]);
      float t1 = (acc[dq][nf][1] + bsv) * S; t1 = t1 > 0.f ? t1 : 0.f; ov.y = t1 * S + bf2f(qv[1]);
      float t2 = (acc[dq][nf][2] + bsv) * S; t2 = t2 > 0.f ? t2 : 0.f; ov.z = t2 * S + bf2f(qv[2]);
      float t3 = (acc[dq][nf][3] + bsv) * S; t3 = t3 > 0.f ? t3 : 0.f; ov.w = t3 * S + bf2f(qv[3]);
      *(float4*)(out + idx) = ov;
    }
  }
}

extern "C" void kernel_launch(void* const* d_in, const int* in_sizes, int n_in,
                              void* d_out, int out_size, void* d_ws, size_t ws_size,
                              hipStream_t stream) {
  const float* x  = (const float*)d_in[0];
  const float* Wq = (const float*)d_in[1];
  const float* bq = (const float*)d_in[2];
  const float* Wk = (const float*)d_in[3];
  const float* bk = (const float*)d_in[4];
  const float* Wv = (const float*)d_in[5];
  const float* bv = (const float*)d_in[6];
  const float* Wc = (const float*)d_in[7];
  const float* bc = (const float*)d_in[8];
  float* out = (float*)d_out;
  u16* ws = (u16*)d_ws;
  const size_t T = (size_t)33554432;
  u16* qb = ws;
  u16* kb = ws + T;
  u16* vb = ws + 2 * T;
  u16* qT = ws + 3 * T;
  u16* kT = ws + 4 * T;
  u16* vT = ws + 5 * T;
  u16* avaT = ws + 6 * T;
  u16* BQ = ws + 7 * T;
  u16* BC = BQ + 331776;
  u16* AVa = qT;
  u16* AVb = kT;
  u16* AVc = vT;

  swz_qkv<<<1296, 256, 0, stream>>>(Wq, Wk, Wv, BQ);
  swz_c<<<1296, 256, 0, stream>>>(Wc, BC);
  conv_qkv<<<4096, 512, 0, stream>>>(x, BQ, bq, bk, bv, qb, kb, vb);
  ktranspose<<<8192, 256, 0, stream>>>(qb, qT, 4096, 64);
  ktranspose<<<8192, 256, 0, stream>>>(kb, kT, 4096, 64);
  ktranspose<<<8192, 256, 0, stream>>>(vb, vT, 4096, 64);
  attn_pair<<<8192, 256, 0, stream>>>(qT, kT, vT, avaT, 64, 4096);
  ktranspose<<<8192, 256, 0, stream>>>(avaT, AVa, 64, 4096);
  attn_pair<<<8192, 256, 0, stream>>>(qb, kb, vb, AVb, 4096, 64);
  attn_pair<<<8192, 256, 0, stream>>>(qb, kb, vb, AVc, 64, 4096);
  conv_final<<<2048, 512, 0, stream>>>(AVa, AVb, AVc, BC, bc, qb, out);
}

// Round 6
// 1010.502 us; speedup vs baseline: 1.5120x; 1.3815x over previous
//
#include <hip/hip_runtime.h>

typedef unsigned short u16;
typedef unsigned int u32;
typedef __attribute__((ext_vector_type(8))) __bf16 bf16x8;
typedef __attribute__((ext_vector_type(4))) float f32x4;
typedef __attribute__((ext_vector_type(4))) u16 u16x4;

#define VOL 262144  // 64^3

__device__ __forceinline__ u16 f2bf(float f) {
  u32 u = __builtin_bit_cast(u32, f);
  u32 r = u + 0x7FFFu + ((u >> 16) & 1u);
  return (u16)(r >> 16);
}
__device__ __forceinline__ float bf2f(u16 h) {
  return __builtin_bit_cast(float, ((u32)h) << 16);
}
__device__ __forceinline__ bf16x8 ldsfrag(const u16* p) { return *(const bf16x8*)p; }

// pitch-64 XOR swizzle for attn buffers.
__device__ __forceinline__ int swA(int row, int col) {
  return row * 64 + (col ^ (((row ^ (row >> 3)) & 7) << 3));
}

// ---------------- weight pre-swizzle: Wq/Wk/Wv -> per-lane B-fragment order ----------------
// K order (s in [0,54)): dh(3) / dw(3) / dd(3) / c32(2).  nf in [0,12): cout group of 16.
__global__ __launch_bounds__(256) void swz_qkv(const float* __restrict__ Wq,
    const float* __restrict__ Wk, const float* __restrict__ Wv, u16* __restrict__ out) {
  int idx = blockIdx.x * 256 + threadIdx.x;
  if (idx >= 54 * 12 * 64 * 8) return;
  int jj = idx & 7;
  int lane = (idx >> 3) & 63;
  int t = idx >> 9;
  int nf = t % 12, s = t / 12;
  int dh = s / 18, sub = s % 18;
  int dw = sub / 6, dd = (sub >> 1) % 3, c32 = sub & 1;
  int coutg = nf * 16 + (lane & 15);
  int cin = c32 * 32 + (lane >> 4) * 8 + jj;
  const float* W = (coutg < 64) ? Wq : ((coutg < 128) ? Wk : Wv);
  int c = coutg & 63;
  out[idx] = f2bf(W[(c * 64 + cin) * 27 + dh * 9 + dw * 3 + dd]);
}

// K order (s in [0,162)): dh(3) / t(3: AVa,AVb,AVc 64-ch block) / dw(3) / dd(3) / c32(2)
__global__ __launch_bounds__(256) void swz_c(const float* __restrict__ Wc, u16* __restrict__ out) {
  int idx = blockIdx.x * 256 + threadIdx.x;
  if (idx >= 162 * 4 * 64 * 8) return;
  int jj = idx & 7;
  int lane = (idx >> 3) & 63;
  int nf = (idx >> 9) & 3;
  int s = idx >> 11;
  int dh = s / 54, rem = s % 54;
  int t = rem / 18, sub = rem % 18;
  int dw = sub / 6, dd = (sub >> 1) % 3, c32 = sub & 1;
  int cout = nf * 16 + (lane & 15);
  int cin = t * 64 + c32 * 32 + (lane >> 4) * 8 + jj;
  out[idx] = f2bf(Wc[(cout * 192 + cin) * 27 + dh * 9 + dw * 3 + dd]);
}

// ---------------- fused q/k/v conv3d (implicit GEMM, BM=128 = 2w x 64d, N=192, 8 waves) ----------------
// Proven round-3 structure: runtime 18-step k-loop, inline div/mod + swizzle, no unroll,
// no P-table (keeps arch VGPR ~64 -> total ~112 -> 2 blocks/CU).
__global__ __launch_bounds__(512, 2) void conv_qkv(const float* __restrict__ x,
    const u16* __restrict__ BQ, const float* __restrict__ bq, const float* __restrict__ bk,
    const float* __restrict__ bv, u16* __restrict__ qb, u16* __restrict__ kb,
    u16* __restrict__ vb) {
  __shared__ __align__(16) u16 xT[4 * 66 * 72];  // [wwi][dpos 0..65][cin swizzled], pitch 72
  int tid = threadIdx.x;
  int id = blockIdx.x;
  int lin = (id & 7) * 512 + (id >> 3);  // XCD-chunk swizzle (4096 = 8*512)
  int b = lin >> 11, h = (lin >> 5) & 63, w0 = (lin & 31) * 2;
  int wave = tid >> 6, lane = tid & 63, r = lane & 15, g = lane >> 4;
  int mhalf = wave >> 2, nq = wave & 3;
  int pairid = tid >> 3, seg = tid & 7;
  if (tid < 256) {  // zero d-pad rows (dpos 0 and 65); swizzle identity there
    int wwi = tid >> 6, ci = tid & 63;
    xT[(wwi * 66 + 0) * 72 + ci] = 0;
    xT[(wwi * 66 + 65) * 72 + ci] = 0;
  }
  f32x4 acc[4][3];
#pragma unroll
  for (int i = 0; i < 4; ++i)
#pragma unroll
    for (int j = 0; j < 3; ++j)
#pragma unroll
      for (int e = 0; e < 4; ++e) acc[i][j][e] = 0.0f;

  for (int dh = 0; dh < 3; ++dh) {
    int hh = h + dh - 1;
    if ((unsigned)hh >= 64u) continue;
    __syncthreads();
#pragma unroll
    for (int pi = 0; pi < 2; ++pi) {
      int pair = pairid + 64 * pi;  // [0,128): wwi(4) x cin-pair(32)
      int wwi = pair >> 5, cin0 = (pair & 31) * 2;
      int ww = w0 + wwi - 1;
      float4 a0{}, a1{}, b0{}, b1{};
      if ((unsigned)ww < 64u) {
        const float* p = x + (size_t)(b * 64 + cin0) * VOL + hh * 4096 + ww * 64 + seg * 8;
        a0 = *(const float4*)p;        a1 = *(const float4*)(p + 4);
        b0 = *(const float4*)(p + VOL); b1 = *(const float4*)(p + VOL + 4);
      }
      u16 ua[8], ub[8];
      ua[0]=f2bf(a0.x); ua[1]=f2bf(a0.y); ua[2]=f2bf(a0.z); ua[3]=f2bf(a0.w);
      ua[4]=f2bf(a1.x); ua[5]=f2bf(a1.y); ua[6]=f2bf(a1.z); ua[7]=f2bf(a1.w);
      ub[0]=f2bf(b0.x); ub[1]=f2bf(b0.y); ub[2]=f2bf(b0.z); ub[3]=f2bf(b0.w);
      ub[4]=f2bf(b1.x); ub[5]=f2bf(b1.y); ub[6]=f2bf(b1.z); ub[7]=f2bf(b1.w);
      int rowb = wwi * 66;
#pragma unroll
      for (int di = 0; di < 8; ++di) {
        int dpos = seg * 8 + di + 1;
        *(u32*)&xT[(rowb + dpos) * 72 + (cin0 ^ (((dpos >> 3) & 7) << 3))] =
            (u32)ua[di] | ((u32)ub[di] << 16);
      }
    }
    __syncthreads();
    for (int sub = 0; sub < 18; ++sub) {
      int dw = sub / 6, dd = (sub >> 1) % 3, c32 = sub & 1;
      int colb = c32 * 32 + g * 8;
      int wwi = mhalf + dw;
      bf16x8 A[4];
#pragma unroll
      for (int l = 0; l < 4; ++l) {
        int dpos = l * 16 + r + dd;
        A[l] = ldsfrag(&xT[(wwi * 66 + dpos) * 72 + (colb ^ (((dpos >> 3) & 7) << 3))]);
      }
      const u16* Bp = BQ + ((size_t)((dh * 18 + sub) * 12 + nq * 3) * 64 + lane) * 8;
#pragma unroll
      for (int nf = 0; nf < 3; ++nf) {
        bf16x8 Bf = *(const bf16x8*)(Bp + nf * 512);
#pragma unroll
        for (int l = 0; l < 4; ++l)
          acc[l][nf] = __builtin_amdgcn_mfma_f32_16x16x32_bf16(A[l], Bf, acc[l][nf], 0, 0, 0);
      }
    }
  }
#pragma unroll
  for (int nf = 0; nf < 3; ++nf) {
    int coutg = (nq * 3 + nf) * 16 + r;
    int ten = coutg >> 6, c = coutg & 63;
    u16* dst = (ten == 0) ? qb : ((ten == 1) ? kb : vb);
    const float* bias = (ten == 0) ? bq : ((ten == 1) ? bk : bv);
    float bsv = bias[c];
#pragma unroll
    for (int l = 0; l < 4; ++l) {
      int d0 = l * 16 + g * 4;
      int idx = (b * 64 + c) * VOL + h * 4096 + (w0 + mhalf) * 64 + d0;
      u16x4 o;
#pragma unroll
      for (int jj = 0; jj < 4; ++jj) o[jj] = f2bf(acc[l][nf][jj] + bsv);
      *(u16x4*)(dst + idx) = o;
    }
  }
}

// ---------------- tiled transpose within each (b,c) volume: src[P][Q] -> dst[Q][P] ----------------
__global__ __launch_bounds__(256, 6) void ktranspose(const u16* __restrict__ src,
    u16* __restrict__ dst, int P, int Q) {
  __shared__ __align__(16) u16 tile[64 * 72];
  int tid = threadIdx.x;
  int id = blockIdx.x;
  int bc = id >> 6, t = id & 63;
  int qt = Q >> 6;
  int p0 = (t / qt) * 64, q0 = (t % qt) * 64;
  const u16* s = src + (size_t)bc * VOL;
  u16* d = dst + (size_t)bc * VOL;
#pragma unroll
  for (int it = 0; it < 2; ++it) {
    int c = tid + 256 * it;
    int i2 = c >> 3, sg = c & 7;
    *(uint4*)&tile[i2 * 72 + ((sg * 8) ^ (((i2 >> 3) & 7) << 3))] =
        *(const uint4*)&s[(size_t)(p0 + i2) * Q + q0 + sg * 8];
  }
  __syncthreads();
  int j = tid >> 2, ms = tid & 3;
  u16 vals[16];
#pragma unroll
  for (int ii = 0; ii < 16; ++ii) {
    int row = ms * 16 + ii;
    vals[ii] = tile[row * 72 + (j ^ (((row >> 3) & 7) << 3))];
  }
  uint4 o0, o1;
  o0.x = (u32)vals[0] | ((u32)vals[1] << 16);
  o0.y = (u32)vals[2] | ((u32)vals[3] << 16);
  o0.z = (u32)vals[4] | ((u32)vals[5] << 16);
  o0.w = (u32)vals[6] | ((u32)vals[7] << 16);
  o1.x = (u32)vals[8] | ((u32)vals[9] << 16);
  o1.y = (u32)vals[10] | ((u32)vals[11] << 16);
  o1.z = (u32)vals[12] | ((u32)vals[13] << 16);
  o1.w = (u32)vals[14] | ((u32)vals[15] << 16);
  size_t drow = (size_t)(q0 + j) * P + p0 + ms * 16;
  *(uint4*)&d[drow] = o0;
  *(uint4*)&d[drow + 8] = o1;
}

// ---------------- axial attention pass-pair on 64x64 slabs ----------------
__global__ __launch_bounds__(256, 2) void attn_pair(const u16* __restrict__ q,
    const u16* __restrict__ k, const u16* __restrict__ v, u16* __restrict__ dst,
    int uStride, int sMul) {
  __shared__ __align__(16) u16 sm[6 * 4096];
  u16* LQ = sm;             u16* LK = sm + 4096;      u16* LV = sm + 2 * 4096;
  u16* LQT = sm + 3 * 4096; u16* LKT = sm + 4 * 4096; u16* LVT = sm + 5 * 4096;
  u16* A1 = LK;   // aliases: K buffers dead after score phase (barrier-protected)
  u16* A2 = LKT;
  int tid = threadIdx.x;
  int id = blockIdx.x;
  int bc = id >> 6, sidx = id & 63;
  size_t base = (size_t)bc * VOL + (size_t)sidx * sMul;
  int wave = tid >> 6, lane = tid & 63, r = lane & 15, g = lane >> 4;
  int pairid = tid >> 3, seg = tid & 7;
  int u0 = pairid * 2;
  const u16* srcs[3] = {q, k, v};
  u16* Ln_[3] = {LQ, LK, LV};
  u16* Lt_[3] = {LQT, LKT, LVT};
#pragma unroll
  for (int t3 = 0; t3 < 3; ++t3) {
    const u16* p = srcs[t3] + base + (size_t)u0 * uStride + seg * 8;
    uint4 ra = *(const uint4*)p;
    uint4 rb = *(const uint4*)(p + uStride);
    *(uint4*)&Ln_[t3][swA(u0, seg * 8)] = ra;
    *(uint4*)&Ln_[t3][swA(u0 + 1, seg * 8)] = rb;
    union { uint4 vv; u16 ss[8]; } Ua, Ub;
    Ua.vv = ra; Ub.vv = rb;
#pragma unroll
    for (int vi = 0; vi < 8; ++vi) {
      int vvx = seg * 8 + vi;
      *(u32*)&Lt_[t3][swA(vvx, u0)] = (u32)Ua.ss[vi] | ((u32)Ub.ss[vi] << 16);
    }
  }
  __syncthreads();
  int row0 = wave * 16;
  f32x4 s1[4], s2[4];
#pragma unroll
  for (int nf = 0; nf < 4; ++nf)
#pragma unroll
    for (int e = 0; e < 4; ++e) { s1[nf][e] = 0.f; s2[nf][e] = 0.f; }
#pragma unroll
  for (int ks = 0; ks < 2; ++ks) {
    int cb = ks * 32 + g * 8;
    bf16x8 aK = ldsfrag(&LK[swA(row0 + r, cb)]);
    bf16x8 aKT = ldsfrag(&LKT[swA(row0 + r, cb)]);
#pragma unroll
    for (int nf = 0; nf < 4; ++nf) {
      bf16x8 bQ = ldsfrag(&LQ[swA(nf * 16 + r, cb)]);
      bf16x8 bQT = ldsfrag(&LQT[swA(nf * 16 + r, cb)]);
      s1[nf] = __builtin_amdgcn_mfma_f32_16x16x32_bf16(aK, bQ, s1[nf], 0, 0, 0);
      s2[nf] = __builtin_amdgcn_mfma_f32_16x16x32_bf16(aKT, bQT, s2[nf], 0, 0, 0);
    }
  }
  __syncthreads();  // all waves done reading LK/LKT before A1/A2 overwrite them
#pragma unroll
  for (int m2 = 0; m2 < 2; ++m2) {
    f32x4* ss = m2 ? s2 : s1;
    u16* Adst = m2 ? A2 : A1;
#pragma unroll
    for (int jj = 0; jj < 4; ++jj) {
      float mx = fmaxf(fmaxf(ss[0][jj], ss[1][jj]), fmaxf(ss[2][jj], ss[3][jj]));
      mx = fmaxf(mx, __shfl_xor(mx, 1, 64));
      mx = fmaxf(mx, __shfl_xor(mx, 2, 64));
      mx = fmaxf(mx, __shfl_xor(mx, 4, 64));
      mx = fmaxf(mx, __shfl_xor(mx, 8, 64));
      float p0 = __expf((ss[0][jj] - mx) * 0.125f);
      float p1 = __expf((ss[1][jj] - mx) * 0.125f);
      float p2 = __expf((ss[2][jj] - mx) * 0.125f);
      float p3 = __expf((ss[3][jj] - mx) * 0.125f);
      float sum = p0 + p1 + p2 + p3;
      sum += __shfl_xor(sum, 1, 64);
      sum += __shfl_xor(sum, 2, 64);
      sum += __shfl_xor(sum, 4, 64);
      sum += __shfl_xor(sum, 8, 64);
      float inv = 1.0f / sum;
      ss[0][jj] = p0 * inv; ss[1][jj] = p1 * inv; ss[2][jj] = p2 * inv; ss[3][jj] = p3 * inv;
    }
    int j0 = row0 + g * 4;
#pragma unroll
    for (int nf = 0; nf < 4; ++nf) {
      int i = nf * 16 + r;
      int a0 = swA(i, j0);
      *(u32*)&Adst[a0]     = (u32)f2bf(ss[nf][0]) | ((u32)f2bf(ss[nf][1]) << 16);
      *(u32*)&Adst[a0 + 2] = (u32)f2bf(ss[nf][2]) | ((u32)f2bf(ss[nf][3]) << 16);
    }
  }
  __syncthreads();
  f32x4 o[4];
#pragma unroll
  for (int nf = 0; nf < 4; ++nf)
#pragma unroll
    for (int e = 0; e < 4; ++e) o[nf][e] = 0.f;
#pragma unroll
  for (int ks = 0; ks < 2; ++ks) {
    int cb = ks * 32 + g * 8;
    bf16x8 aA = ldsfrag(&A1[swA(row0 + r, cb)]);
    bf16x8 aV = ldsfrag(&LV[swA(row0 + r, cb)]);
#pragma unroll
    for (int nf = 0; nf < 4; ++nf) {
      bf16x8 bVT = ldsfrag(&LVT[swA(nf * 16 + r, cb)]);
      bf16x8 bA2 = ldsfrag(&A2[swA(nf * 16 + r, cb)]);
      o[nf] = __builtin_amdgcn_mfma_f32_16x16x32_bf16(aA, bVT, o[nf], 0, 0, 0);
      o[nf] = __builtin_amdgcn_mfma_f32_16x16x32_bf16(aV, bA2, o[nf], 0, 0, 0);
    }
  }
#pragma unroll
  for (int nf = 0; nf < 4; ++nf) {
    int vv = nf * 16 + r;
#pragma unroll
    for (int jj = 0; jj < 4; ++jj) {
      int u = row0 + g * 4 + jj;
      dst[base + (size_t)u * uStride + vv] = f2bf(o[nf][jj] * 0.5f);
    }
  }
}

// ---------------- final conv3d (cin=192 cat, cout=64) + BN + ReLU + BN + residual q ----------------
// 9 phases (3dh x 3t), per-tensor 64-ch pitch-72 staging; runtime 18-step k-loop
// identical in structure to conv_qkv's proven loop (no P-table, no unroll).
__global__ __launch_bounds__(512, 2) void conv_final(const u16* __restrict__ AVa,
    const u16* __restrict__ AVb, const u16* __restrict__ AVc, const u16* __restrict__ BCw,
    const float* __restrict__ bcb, const u16* __restrict__ qb, float* __restrict__ out) {
  __shared__ __align__(16) u16 xT[6 * 66 * 72];  // [wwi 0..5][dpos 0..65][cin64 swizzled]
  int tid = threadIdx.x;
  int id = blockIdx.x;
  int lin = (id & 7) * 256 + (id >> 3);  // 2048 = 8*256
  int b = lin >> 10, h = (lin >> 4) & 63, w0 = (lin & 15) * 4;
  int wave = tid >> 6, lane = tid & 63, r = lane & 15, g = lane >> 4;
  int mw = wave >> 1, nw = wave & 1;
  int pairid = tid >> 3, seg = tid & 7;
  if (tid < 384) {  // zero d-pad rows (dpos 0 and 65); swizzle identity there
    int wwi = tid >> 6, ci = tid & 63;
    xT[(wwi * 66 + 0) * 72 + ci] = 0;
    xT[(wwi * 66 + 65) * 72 + ci] = 0;
  }
  f32x4 acc[4][2];
#pragma unroll
  for (int i = 0; i < 4; ++i)
#pragma unroll
    for (int j = 0; j < 2; ++j)
#pragma unroll
      for (int e = 0; e < 4; ++e) acc[i][j][e] = 0.f;

  for (int dh = 0; dh < 3; ++dh) {
    int hh = h + dh - 1;
    if ((unsigned)hh >= 64u) continue;
    for (int t = 0; t < 3; ++t) {
      const u16* sp = (t == 0) ? AVa : ((t == 1) ? AVb : AVc);
      __syncthreads();
#pragma unroll
      for (int pi = 0; pi < 3; ++pi) {
        int pair = pairid + 64 * pi;  // [0,192): wwi(6) x cin-pair(32)
        int wwi = pair >> 5, cin0 = (pair & 31) * 2;
        int ww = w0 + wwi - 1;
        uint4 ra{}, rb{};
        if ((unsigned)ww < 64u) {
          const u16* p = sp + (size_t)(b * 64 + cin0) * VOL + hh * 4096 + ww * 64 + seg * 8;
          ra = *(const uint4*)p;
          rb = *(const uint4*)(p + VOL);
        }
        union { uint4 vv; u16 ss[8]; } Ua, Ub;
        Ua.vv = ra; Ub.vv = rb;
        int rowb = wwi * 66;
#pragma unroll
        for (int di = 0; di < 8; ++di) {
          int dpos = seg * 8 + di + 1;
          *(u32*)&xT[(rowb + dpos) * 72 + (cin0 ^ (((dpos >> 3) & 7) << 3))] =
              (u32)Ua.ss[di] | ((u32)Ub.ss[di] << 16);
        }
      }
      __syncthreads();
      for (int sub = 0; sub < 18; ++sub) {
        int dw = sub / 6, dd = (sub >> 1) % 3, c32 = sub & 1;
        int colb = c32 * 32 + g * 8;
        int wwi = mw + dw;
        bf16x8 A[4];
#pragma unroll
        for (int dq = 0; dq < 4; ++dq) {
          int dpos = dq * 16 + r + dd;
          A[dq] = ldsfrag(&xT[(wwi * 66 + dpos) * 72 + (colb ^ (((dpos >> 3) & 7) << 3))]);
        }
        const u16* Bp = BCw + ((size_t)(((dh * 3 + t) * 18 + sub) * 4 + nw * 2) * 64 + lane) * 8;
#pragma unroll
        for (int nf = 0; nf < 2; ++nf) {
          bf16x8 Bf = *(const bf16x8*)(Bp + nf * 512);
#pragma unroll
          for (int dq = 0; dq < 4; ++dq)
            acc[dq][nf] = __builtin_amdgcn_mfma_f32_16x16x32_bf16(A[dq], Bf, acc[dq][nf], 0, 0, 0);
        }
      }
    }
  }
  const float S = 0.9999950000374997f;  // 1/sqrt(1+1e-5)
#pragma unroll
  for (int nf = 0; nf < 2; ++nf) {
    int cout = (nw * 2 + nf) * 16 + r;
    float bsv = bcb[cout];
#pragma unroll
    for (int dq = 0; dq < 4; ++dq) {
      int d0 = dq * 16 + g * 4;
      int idx = (b * 64 + cout) * VOL + h * 4096 + (w0 + mw) * 64 + d0;
      u16x4 qv = *(const u16x4*)(qb + idx);
      float4 ov;
      float t0 = (acc[dq][nf][0] + bsv) * S; t0 = t0 > 0.f ? t0 : 0.f; ov.x = t0 * S + bf2f(qv[0]);
      float t1 = (acc[dq][nf][1] + bsv) * S; t1 = t1 > 0.f ? t1 : 0.f; ov.y = t1 * S + bf2f(qv[1]);
      float t2 = (acc[dq][nf][2] + bsv) * S; t2 = t2 > 0.f ? t2 : 0.f; ov.z = t2 * S + bf2f(qv[2]);
      float t3 = (acc[dq][nf][3] + bsv) * S; t3 = t3 > 0.f ? t3 : 0.f; ov.w = t3 * S + bf2f(qv[3]);
      *(float4*)(out + idx) = ov;
    }
  }
}

extern "C" void kernel_launch(void* const* d_in, const int* in_sizes, int n_in,
                              void* d_out, int out_size, void* d_ws, size_t ws_size,
                              hipStream_t stream) {
  const float* x  = (const float*)d_in[0];
  const float* Wq = (const float*)d_in[1];
  const float* bq = (const float*)d_in[2];
  const float* Wk = (const float*)d_in[3];
  const float* bk = (const float*)d_in[4];
  const float* Wv = (const float*)d_in[5];
  const float* bv = (const float*)d_in[6];
  const float* Wc = (const float*)d_in[7];
  const float* bc = (const float*)d_in[8];
  float* out = (float*)d_out;
  u16* ws = (u16*)d_ws;
  const size_t T = (size_t)33554432;
  u16* qb = ws;
  u16* kb = ws + T;
  u16* vb = ws + 2 * T;
  u16* qT = ws + 3 * T;
  u16* kT = ws + 4 * T;
  u16* vT = ws + 5 * T;
  u16* avaT = ws + 6 * T;
  u16* BQ = ws + 7 * T;
  u16* BC = BQ + 331776;
  u16* AVa = qT;
  u16* AVb = kT;
  u16* AVc = vT;

  swz_qkv<<<1296, 256, 0, stream>>>(Wq, Wk, Wv, BQ);
  swz_c<<<1296, 256, 0, stream>>>(Wc, BC);
  conv_qkv<<<4096, 512, 0, stream>>>(x, BQ, bq, bk, bv, qb, kb, vb);
  ktranspose<<<8192, 256, 0, stream>>>(qb, qT, 4096, 64);
  ktranspose<<<8192, 256, 0, stream>>>(kb, kT, 4096, 64);
  ktranspose<<<8192, 256, 0, stream>>>(vb, vT, 4096, 64);
  attn_pair<<<8192, 256, 0, stream>>>(qT, kT, vT, avaT, 64, 4096);
  ktranspose<<<8192, 256, 0, stream>>>(avaT, AVa, 64, 4096);
  attn_pair<<<8192, 256, 0, stream>>>(qb, kb, vb, AVb, 4096, 64);
  attn_pair<<<8192, 256, 0, stream>>>(qb, kb, vb, AVc, 64, 4096);
  conv_final<<<2048, 512, 0, stream>>>(AVa, AVb, AVc, BC, bc, qb, out);
}

// Round 7
// 1005.484 us; speedup vs baseline: 1.5195x; 1.0050x over previous
//
#include <hip/hip_runtime.h>

typedef unsigned short u16;
typedef unsigned int u32;
typedef __attribute__((ext_vector_type(8))) __bf16 bf16x8;
typedef __attribute__((ext_vector_type(4))) float f32x4;
typedef __attribute__((ext_vector_type(4))) u16 u16x4;

#define VOL 262144  // 64^3

__device__ __forceinline__ u16 f2bf(float f) {
  u32 u = __builtin_bit_cast(u32, f);
  u32 r = u + 0x7FFFu + ((u >> 16) & 1u);
  return (u16)(r >> 16);
}
__device__ __forceinline__ float bf2f(u16 h) {
  return __builtin_bit_cast(float, ((u32)h) << 16);
}
__device__ __forceinline__ bf16x8 ldsfrag(const u16* p) { return *(const bf16x8*)p; }

// async 16B/lane global->LDS: LDS dest = uniform base + lane*16, global src per-lane.
__device__ __forceinline__ void gload16(const u16* g, u16* l) {
  __builtin_amdgcn_global_load_lds(
      (const __attribute__((address_space(1))) u32*)g,
      (__attribute__((address_space(3))) u32*)l, 16, 0, 0);
}

// pitch-64 XOR swizzle for attn buffers.
__device__ __forceinline__ int swA(int row, int col) {
  return row * 64 + (col ^ (((row ^ (row >> 3)) & 7) << 3));
}

// ---------------- weight pre-swizzle: Wq/Wk/Wv -> per-lane B-fragment order ----------------
// K order (s in [0,54)): dh(3) / dw(3) / dd(3) / c32(2).  nf in [0,12): cout group of 16.
__global__ __launch_bounds__(256) void swz_qkv(const float* __restrict__ Wq,
    const float* __restrict__ Wk, const float* __restrict__ Wv, u16* __restrict__ out) {
  int idx = blockIdx.x * 256 + threadIdx.x;
  if (idx >= 54 * 12 * 64 * 8) return;
  int jj = idx & 7;
  int lane = (idx >> 3) & 63;
  int t = idx >> 9;
  int nf = t % 12, s = t / 12;
  int dh = s / 18, sub = s % 18;
  int dw = sub / 6, dd = (sub >> 1) % 3, c32 = sub & 1;
  int coutg = nf * 16 + (lane & 15);
  int cin = c32 * 32 + (lane >> 4) * 8 + jj;
  const float* W = (coutg < 64) ? Wq : ((coutg < 128) ? Wk : Wv);
  int c = coutg & 63;
  out[idx] = f2bf(W[(c * 64 + cin) * 27 + dh * 9 + dw * 3 + dd]);
}

// K order (s in [0,162)): dh(3) / t(3: AVa,AVb,AVc 64-ch block) / dw(3) / dd(3) / c32(2)
__global__ __launch_bounds__(256) void swz_c(const float* __restrict__ Wc, u16* __restrict__ out) {
  int idx = blockIdx.x * 256 + threadIdx.x;
  if (idx >= 162 * 4 * 64 * 8) return;
  int jj = idx & 7;
  int lane = (idx >> 3) & 63;
  int nf = (idx >> 9) & 3;
  int s = idx >> 11;
  int dh = s / 54, rem = s % 54;
  int t = rem / 18, sub = rem % 18;
  int dw = sub / 6, dd = (sub >> 1) % 3, c32 = sub & 1;
  int cout = nf * 16 + (lane & 15);
  int cin = t * 64 + c32 * 32 + (lane >> 4) * 8 + jj;
  out[idx] = f2bf(Wc[(cout * 192 + cin) * 27 + dh * 9 + dw * 3 + dd]);
}

// ---------------- x f32 [B,C,H,W,D] -> bf16 channels-last pre-swizzled [B,H,W][d][c^((d&7)<<3)] ----------------
__global__ __launch_bounds__(256, 4) void xcvt(const float* __restrict__ x, u16* __restrict__ xcl) {
  __shared__ __align__(16) u16 tile[4096];
  int id = blockIdx.x;  // (b*64+h)*64 + w
  int b = id >> 12;
  int t = threadIdx.x;
  int c0 = (t & 31) * 2, d0 = (t >> 5) * 8;
  const float* p0 = x + (size_t)(b * 64 + c0) * VOL + (size_t)(id & 4095) * 64 + d0;
  float4 r00 = *(const float4*)p0;
  float4 r01 = *(const float4*)(p0 + 4);
  float4 r10 = *(const float4*)(p0 + VOL);
  float4 r11 = *(const float4*)(p0 + VOL + 4);
  float a0[8] = {r00.x, r00.y, r00.z, r00.w, r01.x, r01.y, r01.z, r01.w};
  float a1[8] = {r10.x, r10.y, r10.z, r10.w, r11.x, r11.y, r11.z, r11.w};
#pragma unroll
  for (int i = 0; i < 8; ++i) {
    int d = d0 + i;
    *(u32*)&tile[d * 64 + (c0 ^ ((d & 7) << 3))] =
        (u32)f2bf(a0[i]) | ((u32)f2bf(a1[i]) << 16);
  }
  __syncthreads();
  u16* dst = xcl + ((size_t)id << 12);
  *(uint4*)&dst[t * 16] = *(const uint4*)&tile[t * 16];
  *(uint4*)&dst[t * 16 + 8] = *(const uint4*)&tile[t * 16 + 8];
}

// ---------------- fused q/k/v conv3d (implicit GEMM, BM=128 = 2w x 64d, N=192, 8 waves) ----------------
// Staging via global_load_lds from channels-last pre-swizzled xcl; double-buffered over dh.
// LDS per buffer: 4 tiles [66 rows][64 cols] (rows 0/65 zero pads, rows 1..64 = d 0..63).
__global__ __launch_bounds__(512, 2) void conv_qkv(const u16* __restrict__ xcl,
    const u16* __restrict__ BQ, const float* __restrict__ bq, const float* __restrict__ bk,
    const float* __restrict__ bv, u16* __restrict__ qb, u16* __restrict__ kb,
    u16* __restrict__ vb) {
  __shared__ __align__(16) u16 xT[2 * 16896];  // 2 buf x 4 tiles x 4224 elems
  int tid = threadIdx.x;
  int id = blockIdx.x;
  int lin = (id & 7) * 512 + (id >> 3);  // XCD-chunk swizzle (4096 = 8*512)
  int b = lin >> 11, h = (lin >> 5) & 63, w0 = (lin & 31) * 2;
  int wave = tid >> 6, lane = tid & 63, r = lane & 15, g = lane >> 4;
  int mhalf = wave >> 2, nq = wave & 3;
  // zero pad rows (dpos 0 and 65) in both buffers
  {
    int tl = tid >> 7, rs = (tid >> 6) & 1, ci = tid & 63;
    int off = tl * 4224 + rs * 65 * 64 + ci;
    xT[off] = 0;
    xT[16896 + off] = 0;
  }
  // zero full OOB tiles (both buffers): tile 0 when w0==0, tile 3 when w0==62
  if (w0 == 0) {
    *(uint4*)&xT[64 + tid * 8] = uint4{0, 0, 0, 0};
    *(uint4*)&xT[16896 + 64 + tid * 8] = uint4{0, 0, 0, 0};
  }
  if (w0 == 62) {
    *(uint4*)&xT[3 * 4224 + 64 + tid * 8] = uint4{0, 0, 0, 0};
    *(uint4*)&xT[16896 + 3 * 4224 + 64 + tid * 8] = uint4{0, 0, 0, 0};
  }
  int tw = wave >> 1, half = wave & 1;  // staging role: wave -> (tile, half)
  int wws = w0 + tw - 1;
  bool doload = (unsigned)wws < 64u;  // wave-uniform

  f32x4 acc[4][3];
#pragma unroll
  for (int i = 0; i < 4; ++i)
#pragma unroll
    for (int j = 0; j < 3; ++j)
#pragma unroll
      for (int e = 0; e < 4; ++e) acc[i][j][e] = 0.0f;

  int dhlo = (h == 0) ? 1 : 0, dhhi = (h == 63) ? 1 : 2;
  // prologue stage
  if (doload) {
    int hh = h + dhlo - 1;
    const u16* gp = xcl + (((size_t)(b * 64 + hh) * 64 + wws) << 12) + (half << 11) + (lane << 3);
    u16* lp = &xT[tw * 4224 + 64 + half * 2048];
#pragma unroll
    for (int j = 0; j < 4; ++j) gload16(gp + j * 512, lp + j * 512);
  }
  int cur = 0;
  for (int dh = dhlo; dh <= dhhi; ++dh) {
    __syncthreads();  // drains vmcnt: buf[cur] ready; prev-phase reads done
    if (dh < dhhi && doload) {  // prefetch next phase into other buffer
      int hh = h + dh;  // (dh+1)-1
      const u16* gp =
          xcl + (((size_t)(b * 64 + hh) * 64 + wws) << 12) + (half << 11) + (lane << 3);
      u16* lp = &xT[(cur ^ 1) * 16896 + tw * 4224 + 64 + half * 2048];
#pragma unroll
      for (int j = 0; j < 4; ++j) gload16(gp + j * 512, lp + j * 512);
    }
    const u16* Bbase = BQ + ((size_t)(dh * 18) * 12 + nq * 3) * 512 + (size_t)lane * 8;
    int bufE = cur * 16896;
    for (int sub = 0; sub < 18; ++sub) {
      int dw = sub / 6, dd = (sub >> 1) % 3, c32 = sub & 1;
      int colb = c32 * 32 + g * 8;
      int wwi = mhalf + dw;
      bf16x8 A[4];
#pragma unroll
      for (int l = 0; l < 4; ++l) {
        int dpos = l * 16 + r + dd;
        A[l] = ldsfrag(&xT[bufE + wwi * 4224 + dpos * 64 + (colb ^ (((dpos - 1) & 7) << 3))]);
      }
      const u16* Bp = Bbase + (size_t)sub * 12 * 512;
#pragma unroll
      for (int nf = 0; nf < 3; ++nf) {
        bf16x8 Bf = *(const bf16x8*)(Bp + nf * 512);
#pragma unroll
        for (int l = 0; l < 4; ++l)
          acc[l][nf] = __builtin_amdgcn_mfma_f32_16x16x32_bf16(A[l], Bf, acc[l][nf], 0, 0, 0);
      }
    }
    cur ^= 1;
  }
#pragma unroll
  for (int nf = 0; nf < 3; ++nf) {
    int coutg = (nq * 3 + nf) * 16 + r;
    int ten = coutg >> 6, c = coutg & 63;
    u16* dst = (ten == 0) ? qb : ((ten == 1) ? kb : vb);
    const float* bias = (ten == 0) ? bq : ((ten == 1) ? bk : bv);
    float bsv = bias[c];
#pragma unroll
    for (int l = 0; l < 4; ++l) {
      int d0 = l * 16 + g * 4;
      int idx = (b * 64 + c) * VOL + h * 4096 + (w0 + mhalf) * 64 + d0;
      u16x4 o;
#pragma unroll
      for (int jj = 0; jj < 4; ++jj) o[jj] = f2bf(acc[l][nf][jj] + bsv);
      *(u16x4*)(dst + idx) = o;
    }
  }
}

// ---------------- tiled transpose within each (b,c) volume: src[P][Q] -> dst[Q][P] ----------------
__global__ __launch_bounds__(256, 6) void ktranspose(const u16* __restrict__ src,
    u16* __restrict__ dst, int P, int Q) {
  __shared__ __align__(16) u16 tile[64 * 72];
  int tid = threadIdx.x;
  int id = blockIdx.x;
  int bc = id >> 6, t = id & 63;
  int qt = Q >> 6;
  int p0 = (t / qt) * 64, q0 = (t % qt) * 64;
  const u16* s = src + (size_t)bc * VOL;
  u16* d = dst + (size_t)bc * VOL;
#pragma unroll
  for (int it = 0; it < 2; ++it) {
    int c = tid + 256 * it;
    int i2 = c >> 3, sg = c & 7;
    *(uint4*)&tile[i2 * 72 + ((sg * 8) ^ (((i2 >> 3) & 7) << 3))] =
        *(const uint4*)&s[(size_t)(p0 + i2) * Q + q0 + sg * 8];
  }
  __syncthreads();
  int j = tid >> 2, ms = tid & 3;
  u16 vals[16];
#pragma unroll
  for (int ii = 0; ii < 16; ++ii) {
    int row = ms * 16 + ii;
    vals[ii] = tile[row * 72 + (j ^ (((row >> 3) & 7) << 3))];
  }
  uint4 o0, o1;
  o0.x = (u32)vals[0] | ((u32)vals[1] << 16);
  o0.y = (u32)vals[2] | ((u32)vals[3] << 16);
  o0.z = (u32)vals[4] | ((u32)vals[5] << 16);
  o0.w = (u32)vals[6] | ((u32)vals[7] << 16);
  o1.x = (u32)vals[8] | ((u32)vals[9] << 16);
  o1.y = (u32)vals[10] | ((u32)vals[11] << 16);
  o1.z = (u32)vals[12] | ((u32)vals[13] << 16);
  o1.w = (u32)vals[14] | ((u32)vals[15] << 16);
  size_t drow = (size_t)(q0 + j) * P + p0 + ms * 16;
  *(uint4*)&d[drow] = o0;
  *(uint4*)&d[drow + 8] = o1;
}

// ---------------- axial attention pass-pair on 64x64 slabs ----------------
__global__ __launch_bounds__(256, 2) void attn_pair(const u16* __restrict__ q,
    const u16* __restrict__ k, const u16* __restrict__ v, u16* __restrict__ dst,
    int uStride, int sMul) {
  __shared__ __align__(16) u16 sm[6 * 4096];
  u16* LQ = sm;             u16* LK = sm + 4096;      u16* LV = sm + 2 * 4096;
  u16* LQT = sm + 3 * 4096; u16* LKT = sm + 4 * 4096; u16* LVT = sm + 5 * 4096;
  u16* A1 = LK;   // aliases: K buffers dead after score phase (barrier-protected)
  u16* A2 = LKT;
  int tid = threadIdx.x;
  int id = blockIdx.x;
  int bc = id >> 6, sidx = id & 63;
  size_t base = (size_t)bc * VOL + (size_t)sidx * sMul;
  int wave = tid >> 6, lane = tid & 63, r = lane & 15, g = lane >> 4;
  int pairid = tid >> 3, seg = tid & 7;
  int u0 = pairid * 2;
  const u16* srcs[3] = {q, k, v};
  u16* Ln_[3] = {LQ, LK, LV};
  u16* Lt_[3] = {LQT, LKT, LVT};
#pragma unroll
  for (int t3 = 0; t3 < 3; ++t3) {
    const u16* p = srcs[t3] + base + (size_t)u0 * uStride + seg * 8;
    uint4 ra = *(const uint4*)p;
    uint4 rb = *(const uint4*)(p + uStride);
    *(uint4*)&Ln_[t3][swA(u0, seg * 8)] = ra;
    *(uint4*)&Ln_[t3][swA(u0 + 1, seg * 8)] = rb;
    union { uint4 vv; u16 ss[8]; } Ua, Ub;
    Ua.vv = ra; Ub.vv = rb;
#pragma unroll
    for (int vi = 0; vi < 8; ++vi) {
      int vvx = seg * 8 + vi;
      *(u32*)&Lt_[t3][swA(vvx, u0)] = (u32)Ua.ss[vi] | ((u32)Ub.ss[vi] << 16);
    }
  }
  __syncthreads();
  int row0 = wave * 16;
  f32x4 s1[4], s2[4];
#pragma unroll
  for (int nf = 0; nf < 4; ++nf)
#pragma unroll
    for (int e = 0; e < 4; ++e) { s1[nf][e] = 0.f; s2[nf][e] = 0.f; }
#pragma unroll
  for (int ks = 0; ks < 2; ++ks) {
    int cb = ks * 32 + g * 8;
    bf16x8 aK = ldsfrag(&LK[swA(row0 + r, cb)]);
    bf16x8 aKT = ldsfrag(&LKT[swA(row0 + r, cb)]);
#pragma unroll
    for (int nf = 0; nf < 4; ++nf) {
      bf16x8 bQ = ldsfrag(&LQ[swA(nf * 16 + r, cb)]);
      bf16x8 bQT = ldsfrag(&LQT[swA(nf * 16 + r, cb)]);
      s1[nf] = __builtin_amdgcn_mfma_f32_16x16x32_bf16(aK, bQ, s1[nf], 0, 0, 0);
      s2[nf] = __builtin_amdgcn_mfma_f32_16x16x32_bf16(aKT, bQT, s2[nf], 0, 0, 0);
    }
  }
  __syncthreads();  // all waves done reading LK/LKT before A1/A2 overwrite them
#pragma unroll
  for (int m2 = 0; m2 < 2; ++m2) {
    f32x4* ss = m2 ? s2 : s1;
    u16* Adst = m2 ? A2 : A1;
#pragma unroll
    for (int jj = 0; jj < 4; ++jj) {
      float mx = fmaxf(fmaxf(ss[0][jj], ss[1][jj]), fmaxf(ss[2][jj], ss[3][jj]));
      mx = fmaxf(mx, __shfl_xor(mx, 1, 64));
      mx = fmaxf(mx, __shfl_xor(mx, 2, 64));
      mx = fmaxf(mx, __shfl_xor(mx, 4, 64));
      mx = fmaxf(mx, __shfl_xor(mx, 8, 64));
      float p0 = __expf((ss[0][jj] - mx) * 0.125f);
      float p1 = __expf((ss[1][jj] - mx) * 0.125f);
      float p2 = __expf((ss[2][jj] - mx) * 0.125f);
      float p3 = __expf((ss[3][jj] - mx) * 0.125f);
      float sum = p0 + p1 + p2 + p3;
      sum += __shfl_xor(sum, 1, 64);
      sum += __shfl_xor(sum, 2, 64);
      sum += __shfl_xor(sum, 4, 64);
      sum += __shfl_xor(sum, 8, 64);
      float inv = 1.0f / sum;
      ss[0][jj] = p0 * inv; ss[1][jj] = p1 * inv; ss[2][jj] = p2 * inv; ss[3][jj] = p3 * inv;
    }
    int j0 = row0 + g * 4;
#pragma unroll
    for (int nf = 0; nf < 4; ++nf) {
      int i = nf * 16 + r;
      int a0 = swA(i, j0);
      *(u32*)&Adst[a0]     = (u32)f2bf(ss[nf][0]) | ((u32)f2bf(ss[nf][1]) << 16);
      *(u32*)&Adst[a0 + 2] = (u32)f2bf(ss[nf][2]) | ((u32)f2bf(ss[nf][3]) << 16);
    }
  }
  __syncthreads();
  f32x4 o[4];
#pragma unroll
  for (int nf = 0; nf < 4; ++nf)
#pragma unroll
    for (int e = 0; e < 4; ++e) o[nf][e] = 0.f;
#pragma unroll
  for (int ks = 0; ks < 2; ++ks) {
    int cb = ks * 32 + g * 8;
    bf16x8 aA = ldsfrag(&A1[swA(row0 + r, cb)]);
    bf16x8 aV = ldsfrag(&LV[swA(row0 + r, cb)]);
#pragma unroll
    for (int nf = 0; nf < 4; ++nf) {
      bf16x8 bVT = ldsfrag(&LVT[swA(nf * 16 + r, cb)]);
      bf16x8 bA2 = ldsfrag(&A2[swA(nf * 16 + r, cb)]);
      o[nf] = __builtin_amdgcn_mfma_f32_16x16x32_bf16(aA, bVT, o[nf], 0, 0, 0);
      o[nf] = __builtin_amdgcn_mfma_f32_16x16x32_bf16(aV, bA2, o[nf], 0, 0, 0);
    }
  }
#pragma unroll
  for (int nf = 0; nf < 4; ++nf) {
    int vv = nf * 16 + r;
#pragma unroll
    for (int jj = 0; jj < 4; ++jj) {
      int u = row0 + g * 4 + jj;
      dst[base + (size_t)u * uStride + vv] = f2bf(o[nf][jj] * 0.5f);
    }
  }
}

// ---------------- final conv3d (cin=192 cat, cout=64) + BN + ReLU + BN + residual q ----------------
// 9 phases (3dh x 3t), per-tensor 64-ch pitch-72 staging; runtime 18-step k-loop.
__global__ __launch_bounds__(512, 2) void conv_final(const u16* __restrict__ AVa,
    const u16* __restrict__ AVb, const u16* __restrict__ AVc, const u16* __restrict__ BCw,
    const float* __restrict__ bcb, const u16* __restrict__ qb, float* __restrict__ out) {
  __shared__ __align__(16) u16 xT[6 * 66 * 72];  // [wwi 0..5][dpos 0..65][cin64 swizzled]
  int tid = threadIdx.x;
  int id = blockIdx.x;
  int lin = (id & 7) * 256 + (id >> 3);  // 2048 = 8*256
  int b = lin >> 10, h = (lin >> 4) & 63, w0 = (lin & 15) * 4;
  int wave = tid >> 6, lane = tid & 63, r = lane & 15, g = lane >> 4;
  int mw = wave >> 1, nw = wave & 1;
  int pairid = tid >> 3, seg = tid & 7;
  if (tid < 384) {  // zero d-pad rows (dpos 0 and 65); swizzle identity there
    int wwi = tid >> 6, ci = tid & 63;
    xT[(wwi * 66 + 0) * 72 + ci] = 0;
    xT[(wwi * 66 + 65) * 72 + ci] = 0;
  }
  f32x4 acc[4][2];
#pragma unroll
  for (int i = 0; i < 4; ++i)
#pragma unroll
    for (int j = 0; j < 2; ++j)
#pragma unroll
      for (int e = 0; e < 4; ++e) acc[i][j][e] = 0.f;

  for (int dh = 0; dh < 3; ++dh) {
    int hh = h + dh - 1;
    if ((unsigned)hh >= 64u) continue;
    for (int t = 0; t < 3; ++t) {
      const u16* sp = (t == 0) ? AVa : ((t == 1) ? AVb : AVc);
      __syncthreads();
#pragma unroll
      for (int pi = 0; pi < 3; ++pi) {
        int pair = pairid + 64 * pi;  // [0,192): wwi(6) x cin-pair(32)
        int wwi = pair >> 5, cin0 = (pair & 31) * 2;
        int ww = w0 + wwi - 1;
        uint4 ra{}, rb{};
        if ((unsigned)ww < 64u) {
          const u16* p = sp + (size_t)(b * 64 + cin0) * VOL + hh * 4096 + ww * 64 + seg * 8;
          ra = *(const uint4*)p;
          rb = *(const uint4*)(p + VOL);
        }
        union { uint4 vv; u16 ss[8]; } Ua, Ub;
        Ua.vv = ra; Ub.vv = rb;
        int rowb = wwi * 66;
#pragma unroll
        for (int di = 0; di < 8; ++di) {
          int dpos = seg * 8 + di + 1;
          *(u32*)&xT[(rowb + dpos) * 72 + (cin0 ^ (((dpos >> 3) & 7) << 3))] =
              (u32)Ua.ss[di] | ((u32)Ub.ss[di] << 16);
        }
      }
      __syncthreads();
      for (int sub = 0; sub < 18; ++sub) {
        int dw = sub / 6, dd = (sub >> 1) % 3, c32 = sub & 1;
        int colb = c32 * 32 + g * 8;
        int wwi = mw + dw;
        bf16x8 A[4];
#pragma unroll
        for (int dq = 0; dq < 4; ++dq) {
          int dpos = dq * 16 + r + dd;
          A[dq] = ldsfrag(&xT[(wwi * 66 + dpos) * 72 + (colb ^ (((dpos >> 3) & 7) << 3))]);
        }
        const u16* Bp = BCw + ((size_t)(((dh * 3 + t) * 18 + sub) * 4 + nw * 2) * 64 + lane) * 8;
#pragma unroll
        for (int nf = 0; nf < 2; ++nf) {
          bf16x8 Bf = *(const bf16x8*)(Bp + nf * 512);
#pragma unroll
          for (int dq = 0; dq < 4; ++dq)
            acc[dq][nf] = __builtin_amdgcn_mfma_f32_16x16x32_bf16(A[dq], Bf, acc[dq][nf], 0, 0, 0);
        }
      }
    }
  }
  const float S = 0.9999950000374997f;  // 1/sqrt(1+1e-5)
#pragma unroll
  for (int nf = 0; nf < 2; ++nf) {
    int cout = (nw * 2 + nf) * 16 + r;
    float bsv = bcb[cout];
#pragma unroll
    for (int dq = 0; dq < 4; ++dq) {
      int d0 = dq * 16 + g * 4;
      int idx = (b * 64 + cout) * VOL + h * 4096 + (w0 + mw) * 64 + d0;
      u16x4 qv = *(const u16x4*)(qb + idx);
      float4 ov;
      float t0 = (acc[dq][nf][0] + bsv) * S; t0 = t0 > 0.f ? t0 : 0.f; ov.x = t0 * S + bf2f(qv[0]);
      float t1 = (acc[dq][nf][1] + bsv) * S; t1 = t1 > 0.f ? t1 : 0.f; ov.y = t1 * S + bf2f(qv[1]);
      float t2 = (acc[dq][nf][2] + bsv) * S; t2 = t2 > 0.f ? t2 : 0.f; ov.z = t2 * S + bf2f(qv[2]);
      float t3 = (acc[dq][nf][3] + bsv) * S; t3 = t3 > 0.f ? t3 : 0.f; ov.w = t3 * S + bf2f(qv[3]);
      *(float4*)(out + idx) = ov;
    }
  }
}

extern "C" void kernel_launch(void* const* d_in, const int* in_sizes, int n_in,
                              void* d_out, int out_size, void* d_ws, size_t ws_size,
                              hipStream_t stream) {
  const float* x  = (const float*)d_in[0];
  const float* Wq = (const float*)d_in[1];
  const float* bq = (const float*)d_in[2];
  const float* Wk = (const float*)d_in[3];
  const float* bk = (const float*)d_in[4];
  const float* Wv = (const float*)d_in[5];
  const float* bv = (const float*)d_in[6];
  const float* Wc = (const float*)d_in[7];
  const float* bc = (const float*)d_in[8];
  float* out = (float*)d_out;
  u16* ws = (u16*)d_ws;
  const size_t T = (size_t)33554432;
  u16* qb = ws;
  u16* kb = ws + T;
  u16* vb = ws + 2 * T;
  u16* qT = ws + 3 * T;
  u16* kT = ws + 4 * T;
  u16* vT = ws + 5 * T;
  u16* xcl = ws + 6 * T;   // channels-last bf16 x; dead after conv_qkv
  u16* avaT = ws + 6 * T;  // pass-1 attn output overwrites xcl (stream-ordered)
  u16* BQ = ws + 7 * T;
  u16* BC = BQ + 331776;
  u16* AVa = qT;  // aliases: qT/kT/vT dead after attn pass 1
  u16* AVb = kT;
  u16* AVc = vT;

  swz_qkv<<<1296, 256, 0, stream>>>(Wq, Wk, Wv, BQ);
  swz_c<<<1296, 256, 0, stream>>>(Wc, BC);
  xcvt<<<8192, 256, 0, stream>>>(x, xcl);
  conv_qkv<<<4096, 512, 0, stream>>>(xcl, BQ, bq, bk, bv, qb, kb, vb);
  ktranspose<<<8192, 256, 0, stream>>>(qb, qT, 4096, 64);
  ktranspose<<<8192, 256, 0, stream>>>(kb, kT, 4096, 64);
  ktranspose<<<8192, 256, 0, stream>>>(vb, vT, 4096, 64);
  attn_pair<<<8192, 256, 0, stream>>>(qT, kT, vT, avaT, 64, 4096);
  ktranspose<<<8192, 256, 0, stream>>>(avaT, AVa, 64, 4096);
  attn_pair<<<8192, 256, 0, stream>>>(qb, kb, vb, AVb, 4096, 64);
  attn_pair<<<8192, 256, 0, stream>>>(qb, kb, vb, AVc, 64, 4096);
  conv_final<<<2048, 512, 0, stream>>>(AVa, AVb, AVc, BC, bc, qb, out);
}